// Round 1
// baseline (339.062 us; speedup 1.0000x reference)
//
#include <hip/hip_runtime.h>
#include <math.h>

#define Bn 32
#define Ln 4096
#define Hn 256
#define Nn 512
#define ROWS (Bn*Nn)   // 16384
#define SLOPEC 0.2f
#define EPSC 1e-8f
#define NEGSENT -1e30f

// ---------------- copy embeddings -> out ----------------
__global__ __launch_bounds__(256) void k_copy(const float* __restrict__ src,
                                              float* __restrict__ dst, long total4) {
    long i = (long)blockIdx.x * blockDim.x + threadIdx.x;
    long stride = (long)gridDim.x * blockDim.x;
    const float4* s = (const float4*)src;
    float4* d = (float4*)dst;
    for (; i < total4; i += stride) d[i] = s[i];
}

// ---------------- span means -> A1 [ROWS][512] ----------------
__global__ __launch_bounds__(256) void k_spans(const float* __restrict__ emb,
        const int* __restrict__ ast, const int* __restrict__ alen,
        const int* __restrict__ ost, const int* __restrict__ olen,
        float* __restrict__ A1) {
    int row = blockIdx.x;
    int h = threadIdx.x;
    int b = row >> 9;
    int as_ = ast[row], al = alen[row];
    int os_ = ost[row], ol = olen[row];
    const float* base = emb + (size_t)b * Ln * Hn + h;
    float asum = 0.f;
    for (int i = 0; i <= al; ++i) asum += base[(size_t)(as_ + i) * Hn];
    float osum = 0.f;
    for (int i = 0; i <= ol; ++i) osum += base[(size_t)(os_ + i) * Hn];
    A1[(size_t)row * 512 + h]       = asum / (float)(al + 1);
    A1[(size_t)row * 512 + 256 + h] = osum / (float)(ol + 1);
}

// ---------------- tiled fp32 GEMM [M,512]@[512,256], 64x64 tiles ----------------
// EPI==0: node projection epilogue (+W_trip[512+sid] row + b_trip)
// EPI==1: GAT epilogue (relu(+b_gat), has_neigh/b_flag select vs node)
template<int EPI>
__global__ __launch_bounds__(256) void k_gemm(
        const float* __restrict__ A, const float* __restrict__ Bw, float* __restrict__ C,
        const float* __restrict__ Wtrip, const float* __restrict__ btrip,
        const int* __restrict__ sid,
        const float* __restrict__ bgat, const int* __restrict__ hneigh,
        const int* __restrict__ bflag, const float* __restrict__ node) {
    __shared__ float Als[32][68];   // k-major, padded (68*4=272B, 16B aligned rows)
    __shared__ float Bls[32][64];
    int tid = threadIdx.x;
    int m0 = blockIdx.x << 6;
    int n0 = blockIdx.y << 6;
    int r0 = (tid & 15) << 2;
    int c0 = (tid >> 4) << 2;
    float acc[4][4] = {};
    for (int kk = 0; kk < 512; kk += 32) {
        __syncthreads();
        #pragma unroll
        for (int p = 0; p < 2; ++p) {   // stage A: 64 rows x 32 k
            int idx = tid + (p << 8);
            int row = idx >> 3;
            int kq = (idx & 7) << 2;
            const float4 v = *(const float4*)(A + (size_t)(m0 + row) * 512 + kk + kq);
            Als[kq + 0][row] = v.x; Als[kq + 1][row] = v.y;
            Als[kq + 2][row] = v.z; Als[kq + 3][row] = v.w;
        }
        #pragma unroll
        for (int p = 0; p < 2; ++p) {   // stage B: 32 k x 64 cols
            int idx = tid + (p << 8);
            int k = idx >> 4;
            int hq = (idx & 15) << 2;
            *(float4*)(&Bls[k][hq]) = *(const float4*)(Bw + (size_t)(kk + k) * 256 + n0 + hq);
        }
        __syncthreads();
        #pragma unroll
        for (int k = 0; k < 32; ++k) {
            float4 a  = *(const float4*)(&Als[k][r0]);
            float4 bv = *(const float4*)(&Bls[k][c0]);
            acc[0][0] += a.x*bv.x; acc[0][1] += a.x*bv.y; acc[0][2] += a.x*bv.z; acc[0][3] += a.x*bv.w;
            acc[1][0] += a.y*bv.x; acc[1][1] += a.y*bv.y; acc[1][2] += a.y*bv.z; acc[1][3] += a.y*bv.w;
            acc[2][0] += a.z*bv.x; acc[2][1] += a.z*bv.y; acc[2][2] += a.z*bv.z; acc[2][3] += a.z*bv.w;
            acc[3][0] += a.w*bv.x; acc[3][1] += a.w*bv.y; acc[3][2] += a.w*bv.z; acc[3][3] += a.w*bv.w;
        }
    }
    #pragma unroll
    for (int i = 0; i < 4; ++i) {
        int row = m0 + r0 + i;
        #pragma unroll
        for (int j = 0; j < 4; ++j) {
            int col = n0 + c0 + j;
            float v = acc[i][j];
            if (EPI == 0) {
                v += Wtrip[(size_t)(512 + sid[row]) * 256 + col] + btrip[col];
                C[(size_t)row * 256 + col] = v;
            } else {
                v += bgat[col];
                v = fmaxf(v, 0.f);
                float res = 0.f;
                if (bflag[row >> 9]) res = hneigh[row] ? v : node[(size_t)row * 256 + col];
                C[(size_t)row * 256 + col] = res;
            }
        }
    }
}

// ---------------- per-node stats: norm, a_tgt, a_src; last block: a_e[2] ----------------
__global__ __launch_bounds__(256) void k_stats(const float* __restrict__ node,
        const float* __restrict__ Wattn, const float* __restrict__ Eemb,
        float* __restrict__ nrm, float* __restrict__ atg, float* __restrict__ asr,
        float* __restrict__ ae) {
    int row = blockIdx.x;
    int tid = threadIdx.x;
    __shared__ float red[3][4];
    if (row < ROWS) {
        float x = node[(size_t)row * 256 + tid];
        float lx = x >= 0.f ? x : SLOPEC * x;
        float ss = x * x;
        float s1 = lx * Wattn[tid];
        float s2 = lx * Wattn[256 + tid];
        #pragma unroll
        for (int o = 32; o; o >>= 1) {
            ss += __shfl_down(ss, o);
            s1 += __shfl_down(s1, o);
            s2 += __shfl_down(s2, o);
        }
        if ((tid & 63) == 0) { int w = tid >> 6; red[0][w] = ss; red[1][w] = s1; red[2][w] = s2; }
        __syncthreads();
        if (tid == 0) {
            nrm[row] = sqrtf(red[0][0] + red[0][1] + red[0][2] + red[0][3]);
            atg[row] = red[1][0] + red[1][1] + red[1][2] + red[1][3];
            asr[row] = red[2][0] + red[2][1] + red[2][2] + red[2][3];
        }
    } else {
        #pragma unroll
        for (int e = 0; e < 2; ++e) {
            float x = Eemb[e * 256 + tid];
            float lx = x >= 0.f ? x : SLOPEC * x;
            float s = lx * Wattn[512 + tid];
            #pragma unroll
            for (int o = 32; o; o >>= 1) s += __shfl_down(s, o);
            if ((tid & 63) == 0) red[0][tid >> 6] = s;
            __syncthreads();
            if (tid == 0) ae[e] = red[0][0] + red[0][1] + red[0][2] + red[0][3];
            __syncthreads();
        }
    }
}

// ---------------- sparse edges + softmax + aggregation; one block per (b,tgt) ----------------
__global__ __launch_bounds__(256) void k_edges(
        const float* __restrict__ node, const float* __restrict__ nrm,
        const float* __restrict__ atg, const float* __restrict__ asr,
        const float* __restrict__ ae, const float* __restrict__ battn,
        const float* __restrict__ Eemb,
        const int* __restrict__ ast, const int* __restrict__ alen,
        const int* __restrict__ ost, const int* __restrict__ olen,
        float* __restrict__ agg, int* __restrict__ hneigh, int* __restrict__ bflag) {
    int tgt = blockIdx.x;
    int b = tgt >> 9;
    int base = b << 9;
    int tid = threadIdx.x;

    __shared__ unsigned long long s_mask[8];
    __shared__ unsigned char s_em[512];
    __shared__ float s_s0[512], s_s1[512];
    __shared__ float s_w0[512], s_w1[512];
    __shared__ float s_red[4];
    __shared__ float s_fin[2];
    __shared__ int s_has;

    int at_s = ast[tgt], at_l = alen[tgt];
    int ot_s = ost[tgt], ot_l = olen[tgt];

    // phase 1: exact span-match candidates (deterministic, ballot-packed)
    #pragma unroll
    for (int p = 0; p < 2; ++p) {
        int lsrc = tid + (p << 8);
        int gs = base + lsrc;
        bool self = (gs == tgt);
        bool sa = (ast[gs] == at_s) && (alen[gs] == at_l) && !self;
        bool so = (ost[gs] == ot_s) && (olen[gs] == ot_l) && !self;
        unsigned char em = (unsigned char)((sa ? 1 : 0) | ((so ? 1 : 0) << 1));
        s_em[lsrc] = em;
        s_w0[lsrc] = 0.f; s_w1[lsrc] = 0.f;
        unsigned long long bal = __ballot(em != 0);
        if ((tid & 63) == 0) s_mask[(p << 2) + (tid >> 6)] = bal;
    }
    __syncthreads();

    float xt = node[(size_t)tgt * 256 + tid];
    float nt = nrm[tgt];

    // phase 2: cooperative exact fp32 cosine per candidate + raw scores
    for (int w = 0; w < 8; ++w) {
        unsigned long long m = s_mask[w];
        while (m) {
            int bit = __builtin_ctzll(m);
            m &= m - 1;
            int lsrc = (w << 6) + bit;
            int gs = base + lsrc;
            float p = xt * node[(size_t)gs * 256 + tid];
            #pragma unroll
            for (int o = 32; o; o >>= 1) p += __shfl_down(p, o);
            if ((tid & 63) == 0) s_red[tid >> 6] = p;
            __syncthreads();
            if (tid == 0) {
                float dot = s_red[0] + s_red[1] + s_red[2] + s_red[3];
                float sim = dot / fmaxf(nt * nrm[gs], EPSC);
                float sc0 = NEGSENT, sc1 = NEGSENT;
                if (sim > 0.f) {
                    float bs = atg[tgt] + asr[gs] + battn[0];
                    unsigned char em = s_em[lsrc];
                    if (em & 1) sc0 = bs + ae[0];
                    if (em & 2) sc1 = bs + ae[1];
                }
                s_s0[lsrc] = sc0; s_s1[lsrc] = sc1;
            }
            __syncthreads();
        }
    }

    // phase 3: softmax over edge list (thread 0; candidate count ~O(1))
    if (tid == 0) {
        float mx = NEGSENT;
        for (int w = 0; w < 8; ++w) {
            unsigned long long m = s_mask[w];
            while (m) {
                int l = (w << 6) + __builtin_ctzll(m); m &= m - 1;
                mx = fmaxf(mx, fmaxf(s_s0[l], s_s1[l]));
            }
        }
        float se0 = 0.f, se1 = 0.f;
        int has = mx > -1e29f ? 1 : 0;
        if (has) {
            float den = 0.f;
            for (int w = 0; w < 8; ++w) {
                unsigned long long m = s_mask[w];
                while (m) {
                    int l = (w << 6) + __builtin_ctzll(m); m &= m - 1;
                    den += expf(s_s0[l] - mx) + expf(s_s1[l] - mx);
                }
            }
            float rden = 1.f / den;
            for (int w = 0; w < 8; ++w) {
                unsigned long long m = s_mask[w];
                while (m) {
                    int l = (w << 6) + __builtin_ctzll(m); m &= m - 1;
                    float e0 = expf(s_s0[l] - mx) * rden;
                    float e1 = expf(s_s1[l] - mx) * rden;
                    s_w0[l] = e0; s_w1[l] = e1;
                    se0 += e0; se1 += e1;
                }
            }
            bflag[b] = 1;
        }
        s_fin[0] = se0; s_fin[1] = se1; s_has = has;
        hneigh[tgt] = has;
    }
    __syncthreads();

    // phase 4: aggregate messages
    float aggn = 0.f;
    for (int w = 0; w < 8; ++w) {
        unsigned long long m = s_mask[w];
        while (m) {
            int lsrc = (w << 6) + __builtin_ctzll(m); m &= m - 1;
            aggn += (s_w0[lsrc] + s_w1[lsrc]) * node[(size_t)(base + lsrc) * 256 + tid];
        }
    }
    float agge = s_fin[0] * Eemb[tid] + s_fin[1] * Eemb[256 + tid];
    agg[(size_t)tgt * 512 + tid]       = aggn;
    agg[(size_t)tgt * 512 + 256 + tid] = agge;
}

// ---------------- deterministic scatter-add at center rows (<128) ----------------
__global__ __launch_bounds__(256) void k_scatter(const float* __restrict__ nadd,
        const int* __restrict__ ast, const int* __restrict__ ost,
        float* __restrict__ out) {
    int b = blockIdx.x >> 7;
    int r = blockIdx.x & 127;
    int tid = threadIdx.x;
    __shared__ int cen[512];
    for (int n = tid; n < 512; n += 256)
        cen[n] = (ast[(b << 9) + n] + ost[(b << 9) + n]) >> 1;
    __syncthreads();
    float acc = 0.f;
    bool any = false;
    for (int n = 0; n < 512; ++n) {
        if (cen[n] == r) { acc += nadd[((size_t)(b << 9) + n) * 256 + tid]; any = true; }
    }
    if (any) {
        size_t o = ((size_t)b * Ln + r) * 256 + tid;
        out[o] += acc;
    }
}

extern "C" void kernel_launch(void* const* d_in, const int* in_sizes, int n_in,
                              void* d_out, int out_size, void* d_ws, size_t ws_size,
                              hipStream_t stream) {
    const float* emb   = (const float*)d_in[0];
    const float* Wtrip = (const float*)d_in[1];
    const float* btrip = (const float*)d_in[2];
    const float* Eemb  = (const float*)d_in[3];
    const float* Wattn = (const float*)d_in[4];
    const float* battn = (const float*)d_in[5];
    const float* Wgat  = (const float*)d_in[6];
    const float* bgat  = (const float*)d_in[7];
    const int* ast  = (const int*)d_in[8];
    const int* alen = (const int*)d_in[9];
    const int* ost  = (const int*)d_in[10];
    const int* olen = (const int*)d_in[11];
    const int* sid  = (const int*)d_in[12];
    float* out = (float*)d_out;

    float* ws   = (float*)d_ws;
    float* A1   = ws;                               // [ROWS*512], reused as agg
    float* node = A1 + (size_t)ROWS * 512;          // [ROWS*256]
    float* nadd = node + (size_t)ROWS * 256;        // [ROWS*256]
    float* nrm  = nadd + (size_t)ROWS * 256;        // [ROWS]
    float* atg  = nrm + ROWS;                       // [ROWS]
    float* asr  = atg + ROWS;                       // [ROWS]
    float* ae   = asr + ROWS;                       // [2]
    int* hneigh = (int*)(ae + 2);                   // [ROWS]
    int* bflag  = hneigh + ROWS;                    // [Bn]
    float* agg  = A1;

    hipMemsetAsync(bflag, 0, Bn * sizeof(int), stream);
    k_copy<<<2048, 256, 0, stream>>>(emb, out, (long)Bn * Ln * Hn / 4);
    k_spans<<<ROWS, 256, 0, stream>>>(emb, ast, alen, ost, olen, A1);
    dim3 g(ROWS / 64, 4);
    k_gemm<0><<<g, 256, 0, stream>>>(A1, Wtrip, node, Wtrip, btrip, sid,
                                     nullptr, nullptr, nullptr, nullptr);
    k_stats<<<ROWS + 1, 256, 0, stream>>>(node, Wattn, Eemb, nrm, atg, asr, ae);
    k_edges<<<ROWS, 256, 0, stream>>>(node, nrm, atg, asr, ae, battn, Eemb,
                                      ast, alen, ost, olen, agg, hneigh, bflag);
    k_gemm<1><<<g, 256, 0, stream>>>(agg, Wgat, nadd, nullptr, nullptr, nullptr,
                                     bgat, hneigh, bflag, node);
    k_scatter<<<Bn * 128, 256, 0, stream>>>(nadd, ast, ost, out);
}

// Round 2
// 265.950 us; speedup vs baseline: 1.2749x; 1.2749x over previous
//
#include <hip/hip_runtime.h>
#include <math.h>

#define Bn 32
#define Ln 4096
#define Hn 256
#define Nn 512
#define ROWS (Bn*Nn)   // 16384
#define LR 136         // emb rows used per batch (st<128, len<8)
#define SLOPEC 0.2f
#define NEGSENT -1e30f

// ---------------- copy embeddings -> out (single-shot, 4x float4/thread) ----------------
__global__ __launch_bounds__(256) void k_copy(const float4* __restrict__ s,
                                              float4* __restrict__ d) {
    long base = (long)blockIdx.x * 1024 + threadIdx.x;
    float4 v0 = s[base];
    float4 v1 = s[base + 256];
    float4 v2 = s[base + 512];
    float4 v3 = s[base + 768];
    d[base]       = v0;
    d[base + 256] = v1;
    d[base + 512] = v2;
    d[base + 768] = v3;
}

// ---------------- PQ = emb[:, :136] @ [Wtrip_top | Wtrip_bot]  (M=4352,K=256,N=512) ----------------
__global__ __launch_bounds__(256) void k_pq(const float* __restrict__ emb,
        const float* __restrict__ Wtrip, float* __restrict__ PQ) {
    __shared__ float Als[32][68];
    __shared__ float Bls[32][64];
    int tid = threadIdx.x;
    int m0 = blockIdx.x << 6;
    int n0 = blockIdx.y << 6;
    int r0 = (tid & 15) << 2;
    int c0 = (tid >> 4) << 2;
    const float* Bbase = Wtrip + ((n0 >= 256) ? 256 * 256 : 0) + (n0 & 255);
    float acc[4][4] = {};
    for (int kk = 0; kk < 256; kk += 32) {
        __syncthreads();
        #pragma unroll
        for (int p = 0; p < 2; ++p) {   // A: 64 rows x 32 k (k-major LDS)
            int idx = tid + (p << 8);
            int row = idx >> 3;
            int kq = (idx & 7) << 2;
            int m = m0 + row;
            int b = m / LR;
            int l = m - b * LR;
            const float4 v = *(const float4*)(emb + (size_t)(b * Ln + l) * 256 + kk + kq);
            Als[kq + 0][row] = v.x; Als[kq + 1][row] = v.y;
            Als[kq + 2][row] = v.z; Als[kq + 3][row] = v.w;
        }
        #pragma unroll
        for (int p = 0; p < 2; ++p) {   // B: 32 k x 64 cols
            int idx = tid + (p << 8);
            int k = idx >> 4;
            int hq = (idx & 15) << 2;
            *(float4*)(&Bls[k][hq]) = *(const float4*)(Bbase + (size_t)(kk + k) * 256 + hq);
        }
        __syncthreads();
        #pragma unroll
        for (int k = 0; k < 32; ++k) {
            float4 a  = *(const float4*)(&Als[k][r0]);
            float4 bv = *(const float4*)(&Bls[k][c0]);
            acc[0][0] += a.x*bv.x; acc[0][1] += a.x*bv.y; acc[0][2] += a.x*bv.z; acc[0][3] += a.x*bv.w;
            acc[1][0] += a.y*bv.x; acc[1][1] += a.y*bv.y; acc[1][2] += a.y*bv.z; acc[1][3] += a.y*bv.w;
            acc[2][0] += a.z*bv.x; acc[2][1] += a.z*bv.y; acc[2][2] += a.z*bv.z; acc[2][3] += a.z*bv.w;
            acc[3][0] += a.w*bv.x; acc[3][1] += a.w*bv.y; acc[3][2] += a.w*bv.z; acc[3][3] += a.w*bv.w;
        }
    }
    #pragma unroll
    for (int i = 0; i < 4; ++i)
        #pragma unroll
        for (int j = 0; j < 4; ++j)
            PQ[(size_t)(m0 + r0 + i) * 512 + n0 + c0 + j] = acc[i][j];
}

// ---------------- nodeW = node @ Wgat[0:256]  (M=16384,K=256,N=256) ----------------
__global__ __launch_bounds__(256) void k_nodeW(const float* __restrict__ A,
        const float* __restrict__ Bw, float* __restrict__ C) {
    __shared__ float Als[32][68];
    __shared__ float Bls[32][64];
    int tid = threadIdx.x;
    int m0 = blockIdx.x << 6;
    int n0 = blockIdx.y << 6;
    int r0 = (tid & 15) << 2;
    int c0 = (tid >> 4) << 2;
    float acc[4][4] = {};
    for (int kk = 0; kk < 256; kk += 32) {
        __syncthreads();
        #pragma unroll
        for (int p = 0; p < 2; ++p) {
            int idx = tid + (p << 8);
            int row = idx >> 3;
            int kq = (idx & 7) << 2;
            const float4 v = *(const float4*)(A + (size_t)(m0 + row) * 256 + kk + kq);
            Als[kq + 0][row] = v.x; Als[kq + 1][row] = v.y;
            Als[kq + 2][row] = v.z; Als[kq + 3][row] = v.w;
        }
        #pragma unroll
        for (int p = 0; p < 2; ++p) {
            int idx = tid + (p << 8);
            int k = idx >> 4;
            int hq = (idx & 15) << 2;
            *(float4*)(&Bls[k][hq]) = *(const float4*)(Bw + (size_t)(kk + k) * 256 + n0 + hq);
        }
        __syncthreads();
        #pragma unroll
        for (int k = 0; k < 32; ++k) {
            float4 a  = *(const float4*)(&Als[k][r0]);
            float4 bv = *(const float4*)(&Bls[k][c0]);
            acc[0][0] += a.x*bv.x; acc[0][1] += a.x*bv.y; acc[0][2] += a.x*bv.z; acc[0][3] += a.x*bv.w;
            acc[1][0] += a.y*bv.x; acc[1][1] += a.y*bv.y; acc[1][2] += a.y*bv.z; acc[1][3] += a.y*bv.w;
            acc[2][0] += a.z*bv.x; acc[2][1] += a.z*bv.y; acc[2][2] += a.z*bv.z; acc[2][3] += a.z*bv.w;
            acc[3][0] += a.w*bv.x; acc[3][1] += a.w*bv.y; acc[3][2] += a.w*bv.z; acc[3][3] += a.w*bv.w;
        }
    }
    #pragma unroll
    for (int i = 0; i < 4; ++i)
        #pragma unroll
        for (int j = 0; j < 4; ++j)
            C[(size_t)(m0 + r0 + i) * 256 + n0 + c0 + j] = acc[i][j];
}

// ---------------- span combine -> node, fused stats (atg/asr); extra block: ae + bflag=0 ----------------
__global__ __launch_bounds__(256) void k_combine(const float* __restrict__ PQ,
        const float* __restrict__ Wtrip, const float* __restrict__ btrip,
        const int* __restrict__ sid,
        const int* __restrict__ ast, const int* __restrict__ alen,
        const int* __restrict__ ost, const int* __restrict__ olen,
        const float* __restrict__ Wattn, const float* __restrict__ Eemb,
        float* __restrict__ node, float* __restrict__ atg, float* __restrict__ asr,
        float* __restrict__ ae, int* __restrict__ bflag) {
    int row = blockIdx.x;
    int tid = threadIdx.x;
    __shared__ float red[2][4];
    if (row < ROWS) {
        int b = row >> 9;
        int as_ = ast[row], al = alen[row];
        int os_ = ost[row], ol = olen[row];
        const float* Pb = PQ + (size_t)b * LR * 512;
        float asum = 0.f;
        for (int i = 0; i <= al; ++i) asum += Pb[(size_t)(as_ + i) * 512 + tid];
        float osum = 0.f;
        for (int i = 0; i <= ol; ++i) osum += Pb[(size_t)(os_ + i) * 512 + 256 + tid];
        float x = asum / (float)(al + 1) + osum / (float)(ol + 1)
                + Wtrip[(size_t)(512 + sid[row]) * 256 + tid] + btrip[tid];
        node[(size_t)row * 256 + tid] = x;
        float lx = x >= 0.f ? x : SLOPEC * x;
        float s1 = lx * Wattn[tid];
        float s2 = lx * Wattn[256 + tid];
        #pragma unroll
        for (int o = 32; o; o >>= 1) {
            s1 += __shfl_down(s1, o);
            s2 += __shfl_down(s2, o);
        }
        if ((tid & 63) == 0) { red[0][tid >> 6] = s1; red[1][tid >> 6] = s2; }
        __syncthreads();
        if (tid == 0) {
            atg[row] = red[0][0] + red[0][1] + red[0][2] + red[0][3];
            asr[row] = red[1][0] + red[1][1] + red[1][2] + red[1][3];
        }
    } else {
        if (tid < Bn) bflag[tid] = 0;
        #pragma unroll
        for (int e = 0; e < 2; ++e) {
            float x = Eemb[e * 256 + tid];
            float lx = x >= 0.f ? x : SLOPEC * x;
            float s = lx * Wattn[512 + tid];
            #pragma unroll
            for (int o = 32; o; o >>= 1) s += __shfl_down(s, o);
            if ((tid & 63) == 0) red[0][tid >> 6] = s;
            __syncthreads();
            if (tid == 0) ae[e] = red[0][0] + red[0][1] + red[0][2] + red[0][3];
            __syncthreads();
        }
    }
}

// ---------------- ve = leaky(edge_emb)... no: ve = edge_emb @ Wgat[256:512] ----------------
__global__ __launch_bounds__(256) void k_ve(const float* __restrict__ Eemb,
        const float* __restrict__ Wgat, float* __restrict__ ve) {
    int tid = threadIdx.x;
    float s0 = 0.f, s1 = 0.f;
    for (int k = 0; k < 256; ++k) {
        float w = Wgat[(size_t)(256 + k) * 256 + tid];
        s0 += Eemb[k] * w;
        s1 += Eemb[256 + k] * w;
    }
    ve[tid] = s0;
    ve[256 + tid] = s1;
}

// ---------------- sparse edges + softmax + fused GAT epilogue ----------------
__global__ __launch_bounds__(256) void k_edges(
        const float* __restrict__ node, const float* __restrict__ nodeW,
        const float* __restrict__ atg, const float* __restrict__ asr,
        const float* __restrict__ ae, const float* __restrict__ battn,
        const float* __restrict__ ve, const float* __restrict__ bgat,
        const int* __restrict__ ast, const int* __restrict__ alen,
        const int* __restrict__ ost, const int* __restrict__ olen,
        float* __restrict__ nadd, int* __restrict__ bflag) {
    int tgt = blockIdx.x;
    int b = tgt >> 9;
    int base = b << 9;
    int tid = threadIdx.x;

    __shared__ unsigned long long s_mask[8];
    __shared__ unsigned char s_em[512];
    __shared__ float s_s0[512], s_s1[512];
    __shared__ float s_w0[512], s_w1[512];
    __shared__ float s_red[4];
    __shared__ float s_fin[2];
    __shared__ int s_has;

    int at_s = ast[tgt], at_l = alen[tgt];
    int ot_s = ost[tgt], ot_l = olen[tgt];

    // phase 1: exact span-match candidates (ballot-packed)
    #pragma unroll
    for (int p = 0; p < 2; ++p) {
        int lsrc = tid + (p << 8);
        int gs = base + lsrc;
        bool self = (gs == tgt);
        bool sa = (ast[gs] == at_s) && (alen[gs] == at_l) && !self;
        bool so = (ost[gs] == ot_s) && (olen[gs] == ot_l) && !self;
        unsigned char em = (unsigned char)((sa ? 1 : 0) | ((so ? 1 : 0) << 1));
        s_em[lsrc] = em;
        s_w0[lsrc] = 0.f; s_w1[lsrc] = 0.f;
        unsigned long long bal = __ballot(em != 0);
        if ((tid & 63) == 0) s_mask[(p << 2) + (tid >> 6)] = bal;
    }
    __syncthreads();

    float xt = node[(size_t)tgt * 256 + tid];

    // phase 2: exact fp32 dot per candidate (sign test == sim>0); raw scores
    for (int w = 0; w < 8; ++w) {
        unsigned long long m = s_mask[w];
        while (m) {
            int bit = __builtin_ctzll(m);
            m &= m - 1;
            int lsrc = (w << 6) + bit;
            int gs = base + lsrc;
            float p = xt * node[(size_t)gs * 256 + tid];
            #pragma unroll
            for (int o = 32; o; o >>= 1) p += __shfl_down(p, o);
            if ((tid & 63) == 0) s_red[tid >> 6] = p;
            __syncthreads();
            if (tid == 0) {
                float dot = s_red[0] + s_red[1] + s_red[2] + s_red[3];
                float sc0 = NEGSENT, sc1 = NEGSENT;
                if (dot > 0.f) {
                    float bs = atg[tgt] + asr[gs] + battn[0];
                    unsigned char em = s_em[lsrc];
                    if (em & 1) sc0 = bs + ae[0];
                    if (em & 2) sc1 = bs + ae[1];
                }
                s_s0[lsrc] = sc0; s_s1[lsrc] = sc1;
            }
            __syncthreads();
        }
    }

    // phase 3: softmax over edge list (thread 0; few candidates)
    if (tid == 0) {
        float mx = NEGSENT;
        for (int w = 0; w < 8; ++w) {
            unsigned long long m = s_mask[w];
            while (m) {
                int l = (w << 6) + __builtin_ctzll(m); m &= m - 1;
                mx = fmaxf(mx, fmaxf(s_s0[l], s_s1[l]));
            }
        }
        float se0 = 0.f, se1 = 0.f;
        int has = mx > -1e29f ? 1 : 0;
        if (has) {
            float den = 0.f;
            for (int w = 0; w < 8; ++w) {
                unsigned long long m = s_mask[w];
                while (m) {
                    int l = (w << 6) + __builtin_ctzll(m); m &= m - 1;
                    den += expf(s_s0[l] - mx) + expf(s_s1[l] - mx);
                }
            }
            float rden = 1.f / den;
            for (int w = 0; w < 8; ++w) {
                unsigned long long m = s_mask[w];
                while (m) {
                    int l = (w << 6) + __builtin_ctzll(m); m &= m - 1;
                    float e0 = expf(s_s0[l] - mx) * rden;
                    float e1 = expf(s_s1[l] - mx) * rden;
                    s_w0[l] = e0; s_w1[l] = e1;
                    se0 += e0; se1 += e1;
                }
            }
            bflag[b] = 1;
        }
        s_fin[0] = se0; s_fin[1] = se1; s_has = has;
    }
    __syncthreads();

    // phase 4: aggregate nodeW + rank-2 edge term, relu, node fallback
    float res;
    if (s_has) {
        float aggW = 0.f;
        for (int w = 0; w < 8; ++w) {
            unsigned long long m = s_mask[w];
            while (m) {
                int lsrc = (w << 6) + __builtin_ctzll(m); m &= m - 1;
                float wt = s_w0[lsrc] + s_w1[lsrc];
                aggW += wt * nodeW[(size_t)(base + lsrc) * 256 + tid];
            }
        }
        float v = aggW + s_fin[0] * ve[tid] + s_fin[1] * ve[256 + tid] + bgat[tid];
        res = fmaxf(v, 0.f);
    } else {
        res = xt;
    }
    nadd[(size_t)tgt * 256 + tid] = res;
}

// ---------------- deterministic scatter-add at center rows (<128), bflag-gated ----------------
__global__ __launch_bounds__(256) void k_scatter(const float* __restrict__ nadd,
        const int* __restrict__ ast, const int* __restrict__ ost,
        const int* __restrict__ bflag, float* __restrict__ out) {
    int b = blockIdx.x >> 7;
    if (!bflag[b]) return;
    int r = blockIdx.x & 127;
    int tid = threadIdx.x;
    __shared__ int cen[512];
    for (int n = tid; n < 512; n += 256)
        cen[n] = (ast[(b << 9) + n] + ost[(b << 9) + n]) >> 1;
    __syncthreads();
    float acc = 0.f;
    bool any = false;
    for (int n = 0; n < 512; ++n) {
        if (cen[n] == r) { acc += nadd[((size_t)(b << 9) + n) * 256 + tid]; any = true; }
    }
    if (any) {
        size_t o = ((size_t)b * Ln + r) * 256 + tid;
        out[o] += acc;
    }
}

extern "C" void kernel_launch(void* const* d_in, const int* in_sizes, int n_in,
                              void* d_out, int out_size, void* d_ws, size_t ws_size,
                              hipStream_t stream) {
    const float* emb   = (const float*)d_in[0];
    const float* Wtrip = (const float*)d_in[1];
    const float* btrip = (const float*)d_in[2];
    const float* Eemb  = (const float*)d_in[3];
    const float* Wattn = (const float*)d_in[4];
    const float* battn = (const float*)d_in[5];
    const float* Wgat  = (const float*)d_in[6];
    const float* bgat  = (const float*)d_in[7];
    const int* ast  = (const int*)d_in[8];
    const int* alen = (const int*)d_in[9];
    const int* ost  = (const int*)d_in[10];
    const int* olen = (const int*)d_in[11];
    const int* sid  = (const int*)d_in[12];
    float* out = (float*)d_out;

    float* ws    = (float*)d_ws;
    float* PQ    = ws;                               // [Bn*LR*512]  8.9 MB
    float* node  = PQ + (size_t)Bn * LR * 512;       // [ROWS*256]  16 MB
    float* nodeW = node + (size_t)ROWS * 256;        // [ROWS*256]  16 MB
    float* nadd  = nodeW + (size_t)ROWS * 256;       // [ROWS*256]  16 MB
    float* atg   = nadd + (size_t)ROWS * 256;        // [ROWS]
    float* asr   = atg + ROWS;                       // [ROWS]
    float* ae    = asr + ROWS;                       // [2]
    float* ve    = ae + 2;                           // [512]
    int* bflag   = (int*)(ve + 512);                 // [Bn]

    k_copy<<<8192, 256, 0, stream>>>((const float4*)emb, (float4*)out);
    k_pq<<<dim3(Bn * LR / 64, 8), 256, 0, stream>>>(emb, Wtrip, PQ);
    k_combine<<<ROWS + 1, 256, 0, stream>>>(PQ, Wtrip, btrip, sid, ast, alen, ost, olen,
                                            Wattn, Eemb, node, atg, asr, ae, bflag);
    k_ve<<<1, 256, 0, stream>>>(Eemb, Wgat, ve);
    k_nodeW<<<dim3(ROWS / 64, 4), 256, 0, stream>>>(node, Wgat, nodeW);
    k_edges<<<ROWS, 256, 0, stream>>>(node, nodeW, atg, asr, ae, battn, ve, bgat,
                                      ast, alen, ost, olen, nadd, bflag);
    k_scatter<<<Bn * 128, 256, 0, stream>>>(nadd, ast, ost, bflag, out);
}

// Round 4
// 234.787 us; speedup vs baseline: 1.4441x; 1.1327x over previous
//
#include <hip/hip_runtime.h>
#include <hip/hip_bf16.h>
#include <math.h>

#define Bn 32
#define Ln 4096
#define Hn 256
#define Nn 512
#define ROWS (Bn*Nn)   // 16384
#define LR 136         // emb rows used per batch (st<128, len<8 -> ed<=134)
#define SLOPEC 0.2f
#define NEGSENT -1e30f
#define CPB 7936       // 32 batches * 248 copy blocks (rows 128..4095, 16 rows/block)

typedef __attribute__((ext_vector_type(8))) short bf16x8;
typedef __attribute__((ext_vector_type(4))) float f32x4;

// ---------------- PQ = emb[:, :136] @ [Wtrip_top | Wtrip_bot]  (M=4352,K=256,N=512) ----------------
__global__ __launch_bounds__(256) void k_pq(const float* __restrict__ emb,
        const float* __restrict__ Wtrip, float* __restrict__ PQ) {
    __shared__ float Als[32][68];
    __shared__ float Bls[32][64];
    int tid = threadIdx.x;
    int m0 = blockIdx.x << 6;
    int n0 = blockIdx.y << 6;
    int r0 = (tid & 15) << 2;
    int c0 = (tid >> 4) << 2;
    const float* Bbase = Wtrip + ((n0 >= 256) ? 256 * 256 : 0) + (n0 & 255);
    float acc[4][4] = {};
    for (int kk = 0; kk < 256; kk += 32) {
        __syncthreads();
        #pragma unroll
        for (int p = 0; p < 2; ++p) {   // A: 64 rows x 32 k (k-major LDS)
            int idx = tid + (p << 8);
            int row = idx >> 3;
            int kq = (idx & 7) << 2;
            int m = m0 + row;
            int b = m / LR;
            int l = m - b * LR;
            const float4 v = *(const float4*)(emb + (size_t)(b * Ln + l) * 256 + kk + kq);
            Als[kq + 0][row] = v.x; Als[kq + 1][row] = v.y;
            Als[kq + 2][row] = v.z; Als[kq + 3][row] = v.w;
        }
        #pragma unroll
        for (int p = 0; p < 2; ++p) {   // B: 32 k x 64 cols
            int idx = tid + (p << 8);
            int k = idx >> 4;
            int hq = (idx & 15) << 2;
            *(float4*)(&Bls[k][hq]) = *(const float4*)(Bbase + (size_t)(kk + k) * 256 + hq);
        }
        __syncthreads();
        #pragma unroll
        for (int k = 0; k < 32; ++k) {
            float4 a  = *(const float4*)(&Als[k][r0]);
            float4 bv = *(const float4*)(&Bls[k][c0]);
            acc[0][0] += a.x*bv.x; acc[0][1] += a.x*bv.y; acc[0][2] += a.x*bv.z; acc[0][3] += a.x*bv.w;
            acc[1][0] += a.y*bv.x; acc[1][1] += a.y*bv.y; acc[1][2] += a.y*bv.z; acc[1][3] += a.y*bv.w;
            acc[2][0] += a.z*bv.x; acc[2][1] += a.z*bv.y; acc[2][2] += a.z*bv.z; acc[2][3] += a.z*bv.w;
            acc[3][0] += a.w*bv.x; acc[3][1] += a.w*bv.y; acc[3][2] += a.w*bv.z; acc[3][3] += a.w*bv.w;
        }
    }
    #pragma unroll
    for (int i = 0; i < 4; ++i)
        #pragma unroll
        for (int j = 0; j < 4; ++j)
            PQ[(size_t)(m0 + r0 + i) * 512 + n0 + c0 + j] = acc[i][j];
}

// ---------------- span combine -> node (fp32) + nodeh (bf16), fused stats;
//                  extra blocks: ae+bflag / ve (8 blocks) / WgT transpose (64 blocks) ----------------
__global__ __launch_bounds__(256) void k_combine(const float* __restrict__ PQ,
        const float* __restrict__ Wtrip, const float* __restrict__ btrip,
        const int* __restrict__ sid,
        const int* __restrict__ ast, const int* __restrict__ alen,
        const int* __restrict__ ost, const int* __restrict__ olen,
        const float* __restrict__ Wattn, const float* __restrict__ Eemb,
        const float* __restrict__ Wgat,
        float* __restrict__ node, __hip_bfloat16* __restrict__ nodeh,
        __hip_bfloat16* __restrict__ WgT,
        float* __restrict__ atg, float* __restrict__ asr,
        float* __restrict__ ae, float* __restrict__ ve, int* __restrict__ bflag) {
    int row = blockIdx.x;
    int tid = threadIdx.x;
    __shared__ float red[2][4];
    __shared__ float vr0[8][32], vr1[8][32];
    if (row < ROWS) {
        int b = row >> 9;
        int as_ = ast[row], al = alen[row];
        int os_ = ost[row], ol = olen[row];
        const float* Pb = PQ + (size_t)b * LR * 512;
        float asum = 0.f;
        for (int i = 0; i <= al; ++i) asum += Pb[(size_t)(as_ + i) * 512 + tid];
        float osum = 0.f;
        for (int i = 0; i <= ol; ++i) osum += Pb[(size_t)(os_ + i) * 512 + 256 + tid];
        float x = asum / (float)(al + 1) + osum / (float)(ol + 1)
                + Wtrip[(size_t)(512 + sid[row]) * 256 + tid] + btrip[tid];
        node[(size_t)row * 256 + tid] = x;
        nodeh[(size_t)row * 256 + tid] = __float2bfloat16(x);
        float lx = x >= 0.f ? x : SLOPEC * x;
        float s1 = lx * Wattn[tid];
        float s2 = lx * Wattn[256 + tid];
        #pragma unroll
        for (int o = 32; o; o >>= 1) {
            s1 += __shfl_down(s1, o);
            s2 += __shfl_down(s2, o);
        }
        if ((tid & 63) == 0) { red[0][tid >> 6] = s1; red[1][tid >> 6] = s2; }
        __syncthreads();
        if (tid == 0) {
            atg[row] = red[0][0] + red[0][1] + red[0][2] + red[0][3];
            asr[row] = red[1][0] + red[1][1] + red[1][2] + red[1][3];
        }
    } else if (row == ROWS) {
        if (tid < Bn) bflag[tid] = 0;
        #pragma unroll
        for (int e = 0; e < 2; ++e) {
            float x = Eemb[e * 256 + tid];
            float lx = x >= 0.f ? x : SLOPEC * x;
            float s = lx * Wattn[512 + tid];
            #pragma unroll
            for (int o = 32; o; o >>= 1) s += __shfl_down(s, o);
            if ((tid & 63) == 0) red[0][tid >> 6] = s;
            __syncthreads();
            if (tid == 0) ae[e] = red[0][0] + red[0][1] + red[0][2] + red[0][3];
            __syncthreads();
        }
    } else if (row <= ROWS + 8) {
        // ve[e][n] = sum_k Eemb[e][k] * Wgat[256+k][n]; 8 blocks x 32 cols
        int j = row - (ROWS + 1);
        int n0 = j << 5;
        int nl = tid & 31, kg = tid >> 5;   // 8 k-groups
        float p0 = 0.f, p1 = 0.f;
        for (int kk = 0; kk < 32; ++kk) {
            int k = (kg << 5) + kk;
            float w = Wgat[(size_t)(256 + k) * 256 + n0 + nl];
            p0 += Eemb[k] * w;
            p1 += Eemb[256 + k] * w;
        }
        vr0[kg][nl] = p0; vr1[kg][nl] = p1;
        __syncthreads();
        if (tid < 32) {
            float s0 = 0.f, s1 = 0.f;
            #pragma unroll
            for (int g = 0; g < 8; ++g) { s0 += vr0[g][tid]; s1 += vr1[g][tid]; }
            ve[n0 + tid] = s0;
            ve[256 + n0 + tid] = s1;
        }
    } else {
        // WgT[n][k] = bf16(Wgat[k][n]) for k<256; 64 blocks x 4 k-rows
        int j = row - (ROWS + 9);
        #pragma unroll
        for (int r = 0; r < 4; ++r) {
            int k = (j << 2) + r;
            float v = Wgat[(size_t)k * 256 + tid];
            WgT[(size_t)tid * 256 + k] = __float2bfloat16(v);
        }
    }
}

// ---------------- nodeW = nodeh @ WgT^T via bf16 MFMA  (M=16384,K=256,N=256) ----------------
__global__ __launch_bounds__(256) void k_nodeW(const __hip_bfloat16* __restrict__ Ah,
        const __hip_bfloat16* __restrict__ BT, float* __restrict__ C) {
    int wave = threadIdx.x >> 6;
    int lane = threadIdx.x & 63;
    int m0 = (blockIdx.x << 6) + (wave << 4);   // wave's 16 output rows
    int n0 = blockIdx.y << 6;
    int fr = lane & 15;
    int kq = (lane >> 4) << 3;
    f32x4 acc[4] = {};
    for (int k0 = 0; k0 < 256; k0 += 32) {
        bf16x8 a = *(const bf16x8*)(Ah + (size_t)(m0 + fr) * 256 + k0 + kq);
        #pragma unroll
        for (int nf = 0; nf < 4; ++nf) {
            bf16x8 b = *(const bf16x8*)(BT + (size_t)(n0 + (nf << 4) + fr) * 256 + k0 + kq);
            acc[nf] = __builtin_amdgcn_mfma_f32_16x16x32_bf16(a, b, acc[nf], 0, 0, 0);
        }
    }
    int r0 = (lane >> 4) << 2;
    #pragma unroll
    for (int nf = 0; nf < 4; ++nf)
        #pragma unroll
        for (int r = 0; r < 4; ++r)
            C[(size_t)(m0 + r0 + r) * 256 + n0 + (nf << 4) + fr] = acc[nf][r];
}

// ---------------- sparse edges + softmax + fused GAT epilogue ----------------
__global__ __launch_bounds__(256) void k_edges(
        const float* __restrict__ node, const float* __restrict__ nodeW,
        const float* __restrict__ atg, const float* __restrict__ asr,
        const float* __restrict__ ae, const float* __restrict__ battn,
        const float* __restrict__ ve, const float* __restrict__ bgat,
        const int* __restrict__ ast, const int* __restrict__ alen,
        const int* __restrict__ ost, const int* __restrict__ olen,
        float* __restrict__ nadd, int* __restrict__ bflag) {
    int tgt = blockIdx.x;
    int b = tgt >> 9;
    int base = b << 9;
    int tid = threadIdx.x;

    __shared__ unsigned long long s_mask[8];
    __shared__ unsigned char s_em[512];
    __shared__ float s_s0[512], s_s1[512];
    __shared__ float s_w0[512], s_w1[512];
    __shared__ float s_red[4];
    __shared__ float s_fin[2];
    __shared__ int s_has;

    int at_s = ast[tgt], at_l = alen[tgt];
    int ot_s = ost[tgt], ot_l = olen[tgt];

    // phase 1: exact span-match candidates (ballot-packed)
    #pragma unroll
    for (int p = 0; p < 2; ++p) {
        int lsrc = tid + (p << 8);
        int gs = base + lsrc;
        bool self = (gs == tgt);
        bool sa = (ast[gs] == at_s) && (alen[gs] == at_l) && !self;
        bool so = (ost[gs] == ot_s) && (olen[gs] == ot_l) && !self;
        unsigned char em = (unsigned char)((sa ? 1 : 0) | ((so ? 1 : 0) << 1));
        s_em[lsrc] = em;
        s_w0[lsrc] = 0.f; s_w1[lsrc] = 0.f;
        unsigned long long bal = __ballot(em != 0);
        if ((tid & 63) == 0) s_mask[(p << 2) + (tid >> 6)] = bal;
    }
    __syncthreads();

    float xt = node[(size_t)tgt * 256 + tid];

    // phase 2: exact fp32 dot per candidate (sign test == sim>0); raw scores
    for (int w = 0; w < 8; ++w) {
        unsigned long long m = s_mask[w];
        while (m) {
            int bit = __builtin_ctzll(m);
            m &= m - 1;
            int lsrc = (w << 6) + bit;
            int gs = base + lsrc;
            float p = xt * node[(size_t)gs * 256 + tid];
            #pragma unroll
            for (int o = 32; o; o >>= 1) p += __shfl_down(p, o);
            if ((tid & 63) == 0) s_red[tid >> 6] = p;
            __syncthreads();
            if (tid == 0) {
                float dot = s_red[0] + s_red[1] + s_red[2] + s_red[3];
                float sc0 = NEGSENT, sc1 = NEGSENT;
                if (dot > 0.f) {
                    float bs = atg[tgt] + asr[gs] + battn[0];
                    unsigned char em = s_em[lsrc];
                    if (em & 1) sc0 = bs + ae[0];
                    if (em & 2) sc1 = bs + ae[1];
                }
                s_s0[lsrc] = sc0; s_s1[lsrc] = sc1;
            }
            __syncthreads();
        }
    }

    // phase 3: softmax over edge list (thread 0; few candidates)
    if (tid == 0) {
        float mx = NEGSENT;
        for (int w = 0; w < 8; ++w) {
            unsigned long long m = s_mask[w];
            while (m) {
                int l = (w << 6) + __builtin_ctzll(m); m &= m - 1;
                mx = fmaxf(mx, fmaxf(s_s0[l], s_s1[l]));
            }
        }
        float se0 = 0.f, se1 = 0.f;
        int has = mx > -1e29f ? 1 : 0;
        if (has) {
            float den = 0.f;
            for (int w = 0; w < 8; ++w) {
                unsigned long long m = s_mask[w];
                while (m) {
                    int l = (w << 6) + __builtin_ctzll(m); m &= m - 1;
                    den += expf(s_s0[l] - mx) + expf(s_s1[l] - mx);
                }
            }
            float rden = 1.f / den;
            for (int w = 0; w < 8; ++w) {
                unsigned long long m = s_mask[w];
                while (m) {
                    int l = (w << 6) + __builtin_ctzll(m); m &= m - 1;
                    float e0 = expf(s_s0[l] - mx) * rden;
                    float e1 = expf(s_s1[l] - mx) * rden;
                    s_w0[l] = e0; s_w1[l] = e1;
                    se0 += e0; se1 += e1;
                }
            }
            bflag[b] = 1;
        }
        s_fin[0] = se0; s_fin[1] = se1; s_has = has;
    }
    __syncthreads();

    // phase 4: aggregate nodeW + rank-2 edge term, relu, node fallback
    float res;
    if (s_has) {
        float aggW = 0.f;
        for (int w = 0; w < 8; ++w) {
            unsigned long long m = s_mask[w];
            while (m) {
                int lsrc = (w << 6) + __builtin_ctzll(m); m &= m - 1;
                float wt = s_w0[lsrc] + s_w1[lsrc];
                aggW += wt * nodeW[(size_t)(base + lsrc) * 256 + tid];
            }
        }
        float v = aggW + s_fin[0] * ve[tid] + s_fin[1] * ve[256 + tid] + bgat[tid];
        res = fmaxf(v, 0.f);
    } else {
        res = xt;
    }
    nadd[(size_t)tgt * 256 + tid] = res;
}

// ---------------- out = emb everywhere; rows<128 get fused scatter-add ----------------
__global__ __launch_bounds__(256) void k_out(const float* __restrict__ emb,
        const float* __restrict__ nadd,
        const int* __restrict__ ast, const int* __restrict__ ost,
        const int* __restrict__ bflag, float* __restrict__ out) {
    int bid = blockIdx.x;
    int tid = threadIdx.x;
    if (bid < CPB) {
        int b = bid / 248;
        int rb = bid - b * 248;
        size_t base = ((size_t)b * Ln + 128 + rb * 16) * 256;   // 16 rows = 1024 float4
        const f32x4* s = (const f32x4*)(emb + base);
        f32x4* d = (f32x4*)(out + base);
        #pragma unroll
        for (int i = 0; i < 4; ++i) {
            f32x4 v = __builtin_nontemporal_load(&s[tid + (i << 8)]);
            __builtin_nontemporal_store(v, &d[tid + (i << 8)]);
        }
    } else {
        int s2 = bid - CPB;
        int b = s2 >> 7;
        int r = s2 & 127;
        __shared__ int cen[512];
        for (int n = tid; n < 512; n += 256)
            cen[n] = (ast[(b << 9) + n] + ost[(b << 9) + n]) >> 1;
        __syncthreads();
        size_t o = ((size_t)b * Ln + r) * 256 + tid;
        float acc = emb[o];
        if (bflag[b]) {
            for (int n = 0; n < 512; ++n)
                if (cen[n] == r) acc += nadd[((size_t)(b << 9) + n) * 256 + tid];
        }
        out[o] = acc;
    }
}

extern "C" void kernel_launch(void* const* d_in, const int* in_sizes, int n_in,
                              void* d_out, int out_size, void* d_ws, size_t ws_size,
                              hipStream_t stream) {
    const float* emb   = (const float*)d_in[0];
    const float* Wtrip = (const float*)d_in[1];
    const float* btrip = (const float*)d_in[2];
    const float* Eemb  = (const float*)d_in[3];
    const float* Wattn = (const float*)d_in[4];
    const float* battn = (const float*)d_in[5];
    const float* Wgat  = (const float*)d_in[6];
    const float* bgat  = (const float*)d_in[7];
    const int* ast  = (const int*)d_in[8];
    const int* alen = (const int*)d_in[9];
    const int* ost  = (const int*)d_in[10];
    const int* olen = (const int*)d_in[11];
    const int* sid  = (const int*)d_in[12];
    float* out = (float*)d_out;

    float* ws    = (float*)d_ws;
    float* PQ    = ws;                                    // [Bn*LR*512]  8.9 MB
    float* node  = PQ + (size_t)Bn * LR * 512;            // [ROWS*256] fp32
    float* nodeW = node + (size_t)ROWS * 256;             // [ROWS*256] fp32
    float* nadd  = nodeW + (size_t)ROWS * 256;            // [ROWS*256] fp32
    float* atg   = nadd + (size_t)ROWS * 256;             // [ROWS]
    float* asr   = atg + ROWS;                            // [ROWS]
    float* ae    = asr + ROWS;                            // [2]
    float* ve    = ae + 2;                                // [512]
    int* bflag   = (int*)(ve + 512);                      // [Bn]
    __hip_bfloat16* nodeh = (__hip_bfloat16*)(bflag + Bn + 32);   // [ROWS*256] bf16
    __hip_bfloat16* WgT   = nodeh + (size_t)ROWS * 256;           // [256*256] bf16

    k_pq<<<dim3(Bn * LR / 64, 8), 256, 0, stream>>>(emb, Wtrip, PQ);
    k_combine<<<ROWS + 73, 256, 0, stream>>>(PQ, Wtrip, btrip, sid, ast, alen, ost, olen,
                                             Wattn, Eemb, Wgat, node, nodeh, WgT,
                                             atg, asr, ae, ve, bflag);
    k_nodeW<<<dim3(ROWS / 64, 4), 256, 0, stream>>>(nodeh, WgT, nodeW);
    k_edges<<<ROWS, 256, 0, stream>>>(node, nodeW, atg, asr, ae, battn, ve, bgat,
                                      ast, alen, ost, olen, nadd, bflag);
    k_out<<<CPB + Bn * 128, 256, 0, stream>>>(emb, nadd, ast, ost, bflag, out);
}

// Round 5
// 184.430 us; speedup vs baseline: 1.8384x; 1.2730x over previous
//
#include <hip/hip_runtime.h>
#include <hip/hip_bf16.h>
#include <math.h>

#define Bn 32
#define Ln 4096
#define Hn 256
#define Nn 512
#define ROWS (Bn*Nn)   // 16384
#define LR 136         // emb rows used per batch (st<128, len<8 -> ed<=134)
#define SLOPEC 0.2f
#define NEGSENT -1e30f
#define CPB 7936       // 32 batches * 248 copy blocks (rows 128..4095, 16 rows/block)

typedef __attribute__((ext_vector_type(8))) short bf16x8;
typedef __attribute__((ext_vector_type(4))) float f32x4;

// ---------------- PQ = emb[:, :136] @ [Wtrip_top | Wtrip_bot]  (M=4352,K=256,N=512) ----------------
__global__ __launch_bounds__(256) void k_pq(const float* __restrict__ emb,
        const float* __restrict__ Wtrip, float* __restrict__ PQ) {
    __shared__ float Als[32][68];
    __shared__ float Bls[32][64];
    int tid = threadIdx.x;
    int m0 = blockIdx.x << 6;
    int n0 = blockIdx.y << 6;
    int r0 = (tid & 15) << 2;
    int c0 = (tid >> 4) << 2;
    const float* Bbase = Wtrip + ((n0 >= 256) ? 256 * 256 : 0) + (n0 & 255);
    float acc[4][4] = {};
    for (int kk = 0; kk < 256; kk += 32) {
        __syncthreads();
        #pragma unroll
        for (int p = 0; p < 2; ++p) {   // A: 64 rows x 32 k (k-major LDS)
            int idx = tid + (p << 8);
            int row = idx >> 3;
            int kq = (idx & 7) << 2;
            int m = m0 + row;
            int b = m / LR;
            int l = m - b * LR;
            const float4 v = *(const float4*)(emb + (size_t)(b * Ln + l) * 256 + kk + kq);
            Als[kq + 0][row] = v.x; Als[kq + 1][row] = v.y;
            Als[kq + 2][row] = v.z; Als[kq + 3][row] = v.w;
        }
        #pragma unroll
        for (int p = 0; p < 2; ++p) {   // B: 32 k x 64 cols
            int idx = tid + (p << 8);
            int k = idx >> 4;
            int hq = (idx & 15) << 2;
            *(float4*)(&Bls[k][hq]) = *(const float4*)(Bbase + (size_t)(kk + k) * 256 + hq);
        }
        __syncthreads();
        #pragma unroll
        for (int k = 0; k < 32; ++k) {
            float4 a  = *(const float4*)(&Als[k][r0]);
            float4 bv = *(const float4*)(&Bls[k][c0]);
            acc[0][0] += a.x*bv.x; acc[0][1] += a.x*bv.y; acc[0][2] += a.x*bv.z; acc[0][3] += a.x*bv.w;
            acc[1][0] += a.y*bv.x; acc[1][1] += a.y*bv.y; acc[1][2] += a.y*bv.z; acc[1][3] += a.y*bv.w;
            acc[2][0] += a.z*bv.x; acc[2][1] += a.z*bv.y; acc[2][2] += a.z*bv.z; acc[2][3] += a.z*bv.w;
            acc[3][0] += a.w*bv.x; acc[3][1] += a.w*bv.y; acc[3][2] += a.w*bv.z; acc[3][3] += a.w*bv.w;
        }
    }
    #pragma unroll
    for (int i = 0; i < 4; ++i)
        #pragma unroll
        for (int j = 0; j < 4; ++j)
            PQ[(size_t)(m0 + r0 + i) * 512 + n0 + c0 + j] = acc[i][j];
}

// ---------------- span combine -> node (fp32) + nodeh (bf16), fused stats;
//                  extra blocks: ae+bflag / ve (8 blocks) / WgT transpose (64 blocks) ----------------
__global__ __launch_bounds__(256) void k_combine(const float* __restrict__ PQ,
        const float* __restrict__ Wtrip, const float* __restrict__ btrip,
        const int* __restrict__ sid,
        const int* __restrict__ ast, const int* __restrict__ alen,
        const int* __restrict__ ost, const int* __restrict__ olen,
        const float* __restrict__ Wattn, const float* __restrict__ Eemb,
        const float* __restrict__ Wgat,
        float* __restrict__ node, __hip_bfloat16* __restrict__ nodeh,
        __hip_bfloat16* __restrict__ WgT,
        float* __restrict__ atg, float* __restrict__ asr,
        float* __restrict__ ae, float* __restrict__ ve, int* __restrict__ bflag) {
    int row = blockIdx.x;
    int tid = threadIdx.x;
    __shared__ float red[2][4];
    __shared__ float vr0[8][32], vr1[8][32];
    if (row < ROWS) {
        int b = row >> 9;
        int as_ = ast[row], al = alen[row];
        int os_ = ost[row], ol = olen[row];
        const float* Pb = PQ + (size_t)b * LR * 512;
        float asum = 0.f;
        for (int i = 0; i <= al; ++i) asum += Pb[(size_t)(as_ + i) * 512 + tid];
        float osum = 0.f;
        for (int i = 0; i <= ol; ++i) osum += Pb[(size_t)(os_ + i) * 512 + 256 + tid];
        float x = asum / (float)(al + 1) + osum / (float)(ol + 1)
                + Wtrip[(size_t)(512 + sid[row]) * 256 + tid] + btrip[tid];
        node[(size_t)row * 256 + tid] = x;
        nodeh[(size_t)row * 256 + tid] = __float2bfloat16(x);
        float lx = x >= 0.f ? x : SLOPEC * x;
        float s1 = lx * Wattn[tid];
        float s2 = lx * Wattn[256 + tid];
        #pragma unroll
        for (int o = 32; o; o >>= 1) {
            s1 += __shfl_down(s1, o);
            s2 += __shfl_down(s2, o);
        }
        if ((tid & 63) == 0) { red[0][tid >> 6] = s1; red[1][tid >> 6] = s2; }
        __syncthreads();
        if (tid == 0) {
            atg[row] = red[0][0] + red[0][1] + red[0][2] + red[0][3];
            asr[row] = red[1][0] + red[1][1] + red[1][2] + red[1][3];
        }
    } else if (row == ROWS) {
        if (tid < Bn) bflag[tid] = 0;
        #pragma unroll
        for (int e = 0; e < 2; ++e) {
            float x = Eemb[e * 256 + tid];
            float lx = x >= 0.f ? x : SLOPEC * x;
            float s = lx * Wattn[512 + tid];
            #pragma unroll
            for (int o = 32; o; o >>= 1) s += __shfl_down(s, o);
            if ((tid & 63) == 0) red[0][tid >> 6] = s;
            __syncthreads();
            if (tid == 0) ae[e] = red[0][0] + red[0][1] + red[0][2] + red[0][3];
            __syncthreads();
        }
    } else if (row <= ROWS + 8) {
        // ve[e][n] = sum_k Eemb[e][k] * Wgat[256+k][n]; 8 blocks x 32 cols
        int j = row - (ROWS + 1);
        int n0 = j << 5;
        int nl = tid & 31, kg = tid >> 5;   // 8 k-groups
        float p0 = 0.f, p1 = 0.f;
        for (int kk = 0; kk < 32; ++kk) {
            int k = (kg << 5) + kk;
            float w = Wgat[(size_t)(256 + k) * 256 + n0 + nl];
            p0 += Eemb[k] * w;
            p1 += Eemb[256 + k] * w;
        }
        vr0[kg][nl] = p0; vr1[kg][nl] = p1;
        __syncthreads();
        if (tid < 32) {
            float s0 = 0.f, s1 = 0.f;
            #pragma unroll
            for (int g = 0; g < 8; ++g) { s0 += vr0[g][tid]; s1 += vr1[g][tid]; }
            ve[n0 + tid] = s0;
            ve[256 + n0 + tid] = s1;
        }
    } else {
        // WgT[n][k] = bf16(Wgat[k][n]) for k<256; 64 blocks x 4 k-rows
        int j = row - (ROWS + 9);
        #pragma unroll
        for (int r = 0; r < 4; ++r) {
            int k = (j << 2) + r;
            float v = Wgat[(size_t)k * 256 + tid];
            WgT[(size_t)tid * 256 + k] = __float2bfloat16(v);
        }
    }
}

// ---------------- nodeW = nodeh @ WgT^T via bf16 MFMA  (M=16384,K=256,N=256) ----------------
__global__ __launch_bounds__(256) void k_nodeW(const __hip_bfloat16* __restrict__ Ah,
        const __hip_bfloat16* __restrict__ BT, float* __restrict__ C) {
    int wave = threadIdx.x >> 6;
    int lane = threadIdx.x & 63;
    int m0 = (blockIdx.x << 6) + (wave << 4);   // wave's 16 output rows
    int n0 = blockIdx.y << 6;
    int fr = lane & 15;
    int kq = (lane >> 4) << 3;
    f32x4 acc[4] = {};
    for (int k0 = 0; k0 < 256; k0 += 32) {
        bf16x8 a = *(const bf16x8*)(Ah + (size_t)(m0 + fr) * 256 + k0 + kq);
        #pragma unroll
        for (int nf = 0; nf < 4; ++nf) {
            bf16x8 b = *(const bf16x8*)(BT + (size_t)(n0 + (nf << 4) + fr) * 256 + k0 + kq);
            acc[nf] = __builtin_amdgcn_mfma_f32_16x16x32_bf16(a, b, acc[nf], 0, 0, 0);
        }
    }
    int r0 = (lane >> 4) << 2;
    #pragma unroll
    for (int nf = 0; nf < 4; ++nf)
        #pragma unroll
        for (int r = 0; r < 4; ++r)
            C[(size_t)(m0 + r0 + r) * 256 + n0 + (nf << 4) + fr] = acc[nf][r];
}

// ---------------- sparse edges + softmax + fused GAT epilogue;
//                  tail blocks (bid >= ROWS): bulk copy out rows 128..4095 ----------------
__global__ __launch_bounds__(256) void k_edges(
        const float* __restrict__ node, const float* __restrict__ nodeW,
        const float* __restrict__ atg, const float* __restrict__ asr,
        const float* __restrict__ ae, const float* __restrict__ battn,
        const float* __restrict__ ve, const float* __restrict__ bgat,
        const int* __restrict__ ast, const int* __restrict__ alen,
        const int* __restrict__ ost, const int* __restrict__ olen,
        const float* __restrict__ emb, float* __restrict__ out,
        float* __restrict__ nadd, int* __restrict__ bflag) {
    int bid = blockIdx.x;
    int tid = threadIdx.x;

    if (bid >= ROWS) {
        // plain copy (L3-friendly): 16 rows = 1024 float4 per block
        int cb = bid - ROWS;
        int b = cb / 248;
        int rb = cb - b * 248;
        size_t base = ((size_t)b * Ln + 128 + rb * 16) * 256;
        const f32x4* s = (const f32x4*)(emb + base);
        f32x4* d = (f32x4*)(out + base);
        #pragma unroll
        for (int i = 0; i < 4; ++i)
            d[tid + (i << 8)] = s[tid + (i << 8)];
        return;
    }

    int tgt = bid;
    int b = tgt >> 9;
    int base = b << 9;

    __shared__ unsigned long long s_mask[8];
    __shared__ unsigned char s_em[512];
    __shared__ float s_s0[512], s_s1[512];
    __shared__ float s_w0[512], s_w1[512];
    __shared__ float s_red[4];
    __shared__ float s_fin[2];
    __shared__ int s_has;

    int at_s = ast[tgt], at_l = alen[tgt];
    int ot_s = ost[tgt], ot_l = olen[tgt];

    // phase 1: exact span-match candidates (ballot-packed)
    #pragma unroll
    for (int p = 0; p < 2; ++p) {
        int lsrc = tid + (p << 8);
        int gs = base + lsrc;
        bool self = (gs == tgt);
        bool sa = (ast[gs] == at_s) && (alen[gs] == at_l) && !self;
        bool so = (ost[gs] == ot_s) && (olen[gs] == ot_l) && !self;
        unsigned char em = (unsigned char)((sa ? 1 : 0) | ((so ? 1 : 0) << 1));
        s_em[lsrc] = em;
        s_w0[lsrc] = 0.f; s_w1[lsrc] = 0.f;
        unsigned long long bal = __ballot(em != 0);
        if ((tid & 63) == 0) s_mask[(p << 2) + (tid >> 6)] = bal;
    }
    __syncthreads();

    float xt = node[(size_t)tgt * 256 + tid];

    // phase 2: exact fp32 dot per candidate (sign test == sim>0); raw scores
    for (int w = 0; w < 8; ++w) {
        unsigned long long m = s_mask[w];
        while (m) {
            int bit = __builtin_ctzll(m);
            m &= m - 1;
            int lsrc = (w << 6) + bit;
            int gs = base + lsrc;
            float p = xt * node[(size_t)gs * 256 + tid];
            #pragma unroll
            for (int o = 32; o; o >>= 1) p += __shfl_down(p, o);
            if ((tid & 63) == 0) s_red[tid >> 6] = p;
            __syncthreads();
            if (tid == 0) {
                float dot = s_red[0] + s_red[1] + s_red[2] + s_red[3];
                float sc0 = NEGSENT, sc1 = NEGSENT;
                if (dot > 0.f) {
                    float bs = atg[tgt] + asr[gs] + battn[0];
                    unsigned char em = s_em[lsrc];
                    if (em & 1) sc0 = bs + ae[0];
                    if (em & 2) sc1 = bs + ae[1];
                }
                s_s0[lsrc] = sc0; s_s1[lsrc] = sc1;
            }
            __syncthreads();
        }
    }

    // phase 3: softmax over edge list (thread 0; few candidates)
    if (tid == 0) {
        float mx = NEGSENT;
        for (int w = 0; w < 8; ++w) {
            unsigned long long m = s_mask[w];
            while (m) {
                int l = (w << 6) + __builtin_ctzll(m); m &= m - 1;
                mx = fmaxf(mx, fmaxf(s_s0[l], s_s1[l]));
            }
        }
        float se0 = 0.f, se1 = 0.f;
        int has = mx > -1e29f ? 1 : 0;
        if (has) {
            float den = 0.f;
            for (int w = 0; w < 8; ++w) {
                unsigned long long m = s_mask[w];
                while (m) {
                    int l = (w << 6) + __builtin_ctzll(m); m &= m - 1;
                    den += expf(s_s0[l] - mx) + expf(s_s1[l] - mx);
                }
            }
            float rden = 1.f / den;
            for (int w = 0; w < 8; ++w) {
                unsigned long long m = s_mask[w];
                while (m) {
                    int l = (w << 6) + __builtin_ctzll(m); m &= m - 1;
                    float e0 = expf(s_s0[l] - mx) * rden;
                    float e1 = expf(s_s1[l] - mx) * rden;
                    s_w0[l] = e0; s_w1[l] = e1;
                    se0 += e0; se1 += e1;
                }
            }
            bflag[b] = 1;
        }
        s_fin[0] = se0; s_fin[1] = se1; s_has = has;
    }
    __syncthreads();

    // phase 4: aggregate nodeW + rank-2 edge term, relu, node fallback
    float res;
    if (s_has) {
        float aggW = 0.f;
        for (int w = 0; w < 8; ++w) {
            unsigned long long m = s_mask[w];
            while (m) {
                int lsrc = (w << 6) + __builtin_ctzll(m); m &= m - 1;
                float wt = s_w0[lsrc] + s_w1[lsrc];
                aggW += wt * nodeW[(size_t)(base + lsrc) * 256 + tid];
            }
        }
        float v = aggW + s_fin[0] * ve[tid] + s_fin[1] * ve[256 + tid] + bgat[tid];
        res = fmaxf(v, 0.f);
    } else {
        res = xt;
    }
    nadd[(size_t)tgt * 256 + tid] = res;
}

// ---------------- out rows<128: emb + ballot-gathered scatter-add ----------------
__global__ __launch_bounds__(256) void k_scatter(const float* __restrict__ emb,
        const float* __restrict__ nadd,
        const int* __restrict__ ast, const int* __restrict__ ost,
        const int* __restrict__ bflag, float* __restrict__ out) {
    int b = blockIdx.x >> 7;
    int r = blockIdx.x & 127;
    int tid = threadIdx.x;
    __shared__ int cen[512];
    __shared__ unsigned long long s_mask[8];
    for (int n = tid; n < 512; n += 256)
        cen[n] = (ast[(b << 9) + n] + ost[(b << 9) + n]) >> 1;
    __syncthreads();
    #pragma unroll
    for (int p = 0; p < 2; ++p) {
        int n = tid + (p << 8);
        unsigned long long bal = __ballot(cen[n] == r);
        if ((tid & 63) == 0) s_mask[(p << 2) + (tid >> 6)] = bal;
    }
    __syncthreads();
    size_t o = ((size_t)b * Ln + r) * 256 + tid;
    float acc = emb[o];
    if (bflag[b]) {
        for (int w = 0; w < 8; ++w) {
            unsigned long long m = s_mask[w];
            while (m) {
                int n = (w << 6) + __builtin_ctzll(m); m &= m - 1;
                acc += nadd[((size_t)(b << 9) + n) * 256 + tid];
            }
        }
    }
    out[o] = acc;
}

extern "C" void kernel_launch(void* const* d_in, const int* in_sizes, int n_in,
                              void* d_out, int out_size, void* d_ws, size_t ws_size,
                              hipStream_t stream) {
    const float* emb   = (const float*)d_in[0];
    const float* Wtrip = (const float*)d_in[1];
    const float* btrip = (const float*)d_in[2];
    const float* Eemb  = (const float*)d_in[3];
    const float* Wattn = (const float*)d_in[4];
    const float* battn = (const float*)d_in[5];
    const float* Wgat  = (const float*)d_in[6];
    const float* bgat  = (const float*)d_in[7];
    const int* ast  = (const int*)d_in[8];
    const int* alen = (const int*)d_in[9];
    const int* ost  = (const int*)d_in[10];
    const int* olen = (const int*)d_in[11];
    const int* sid  = (const int*)d_in[12];
    float* out = (float*)d_out;

    float* ws    = (float*)d_ws;
    float* PQ    = ws;                                    // [Bn*LR*512]  8.9 MB
    float* node  = PQ + (size_t)Bn * LR * 512;            // [ROWS*256] fp32
    float* nodeW = node + (size_t)ROWS * 256;             // [ROWS*256] fp32
    float* nadd  = nodeW + (size_t)ROWS * 256;            // [ROWS*256] fp32
    float* atg   = nadd + (size_t)ROWS * 256;             // [ROWS]
    float* asr   = atg + ROWS;                            // [ROWS]
    float* ae    = asr + ROWS;                            // [2]
    float* ve    = ae + 2;                                // [512]
    int* bflag   = (int*)(ve + 512);                      // [Bn]
    __hip_bfloat16* nodeh = (__hip_bfloat16*)(bflag + Bn + 32);   // [ROWS*256] bf16
    __hip_bfloat16* WgT   = nodeh + (size_t)ROWS * 256;           // [256*256] bf16

    k_pq<<<dim3(Bn * LR / 64, 8), 256, 0, stream>>>(emb, Wtrip, PQ);
    k_combine<<<ROWS + 73, 256, 0, stream>>>(PQ, Wtrip, btrip, sid, ast, alen, ost, olen,
                                             Wattn, Eemb, Wgat, node, nodeh, WgT,
                                             atg, asr, ae, ve, bflag);
    k_nodeW<<<dim3(ROWS / 64, 4), 256, 0, stream>>>(nodeh, WgT, nodeW);
    k_edges<<<ROWS + CPB, 256, 0, stream>>>(node, nodeW, atg, asr, ae, battn, ve, bgat,
                                            ast, alen, ost, olen, emb, out, nadd, bflag);
    k_scatter<<<Bn * 128, 256, 0, stream>>>(emb, nadd, ast, ost, bflag, out);
}

// Round 6
// 175.304 us; speedup vs baseline: 1.9341x; 1.0521x over previous
//
#include <hip/hip_runtime.h>
#include <hip/hip_bf16.h>
#include <math.h>

#define Bn 32
#define Ln 4096
#define Hn 256
#define Nn 512
#define ROWS (Bn*Nn)   // 16384
#define LR 136         // emb rows used per batch (st<128, len<8 -> ed<=134)
#define SLOPEC 0.2f
#define NEGSENT -1e30f
#define CROWS (Bn*(Ln-128))   // 126976 rows to bulk-copy (rows 128..4095)

typedef __attribute__((ext_vector_type(8))) short bf16x8;
typedef __attribute__((ext_vector_type(4))) float f32x4;

// ---------------- PQ = emb[:, :136] @ [Wtrip_top | Wtrip_bot]  (M=4352,K=256,N=512) ----------------
__global__ __launch_bounds__(256) void k_pq(const float* __restrict__ emb,
        const float* __restrict__ Wtrip, float* __restrict__ PQ) {
    __shared__ float Als[32][68];
    __shared__ float Bls[32][64];
    int tid = threadIdx.x;
    int m0 = blockIdx.x << 6;
    int n0 = blockIdx.y << 6;
    int r0 = (tid & 15) << 2;
    int c0 = (tid >> 4) << 2;
    const float* Bbase = Wtrip + ((n0 >= 256) ? 256 * 256 : 0) + (n0 & 255);
    float acc[4][4] = {};
    for (int kk = 0; kk < 256; kk += 32) {
        __syncthreads();
        #pragma unroll
        for (int p = 0; p < 2; ++p) {   // A: 64 rows x 32 k (k-major LDS)
            int idx = tid + (p << 8);
            int row = idx >> 3;
            int kq = (idx & 7) << 2;
            int m = m0 + row;
            int b = m / LR;
            int l = m - b * LR;
            const float4 v = *(const float4*)(emb + (size_t)(b * Ln + l) * 256 + kk + kq);
            Als[kq + 0][row] = v.x; Als[kq + 1][row] = v.y;
            Als[kq + 2][row] = v.z; Als[kq + 3][row] = v.w;
        }
        #pragma unroll
        for (int p = 0; p < 2; ++p) {   // B: 32 k x 64 cols
            int idx = tid + (p << 8);
            int k = idx >> 4;
            int hq = (idx & 15) << 2;
            *(float4*)(&Bls[k][hq]) = *(const float4*)(Bbase + (size_t)(kk + k) * 256 + hq);
        }
        __syncthreads();
        #pragma unroll
        for (int k = 0; k < 32; ++k) {
            float4 a  = *(const float4*)(&Als[k][r0]);
            float4 bv = *(const float4*)(&Bls[k][c0]);
            acc[0][0] += a.x*bv.x; acc[0][1] += a.x*bv.y; acc[0][2] += a.x*bv.z; acc[0][3] += a.x*bv.w;
            acc[1][0] += a.y*bv.x; acc[1][1] += a.y*bv.y; acc[1][2] += a.y*bv.z; acc[1][3] += a.y*bv.w;
            acc[2][0] += a.z*bv.x; acc[2][1] += a.z*bv.y; acc[2][2] += a.z*bv.z; acc[2][3] += a.z*bv.w;
            acc[3][0] += a.w*bv.x; acc[3][1] += a.w*bv.y; acc[3][2] += a.w*bv.z; acc[3][3] += a.w*bv.w;
        }
    }
    #pragma unroll
    for (int i = 0; i < 4; ++i)
        #pragma unroll
        for (int j = 0; j < 4; ++j)
            PQ[(size_t)(m0 + r0 + i) * 512 + n0 + c0 + j] = acc[i][j];
}

// ---------------- span combine -> node (fp32) + nodeh (bf16), fused stats;
//                  extra blocks: ae+bflag / ve (8 blocks) / WgT transpose (64 blocks) ----------------
__global__ __launch_bounds__(256) void k_combine(const float* __restrict__ PQ,
        const float* __restrict__ Wtrip, const float* __restrict__ btrip,
        const int* __restrict__ sid,
        const int* __restrict__ ast, const int* __restrict__ alen,
        const int* __restrict__ ost, const int* __restrict__ olen,
        const float* __restrict__ Wattn, const float* __restrict__ Eemb,
        const float* __restrict__ Wgat,
        float* __restrict__ node, __hip_bfloat16* __restrict__ nodeh,
        __hip_bfloat16* __restrict__ WgT,
        float* __restrict__ atg, float* __restrict__ asr,
        float* __restrict__ ae, float* __restrict__ ve, int* __restrict__ bflag) {
    int row = blockIdx.x;
    int tid = threadIdx.x;
    __shared__ float red[2][4];
    __shared__ float vr0[8][32], vr1[8][32];
    if (row < ROWS) {
        int b = row >> 9;
        int as_ = ast[row], al = alen[row];
        int os_ = ost[row], ol = olen[row];
        const float* Pb = PQ + (size_t)b * LR * 512;
        float asum = 0.f;
        for (int i = 0; i <= al; ++i) asum += Pb[(size_t)(as_ + i) * 512 + tid];
        float osum = 0.f;
        for (int i = 0; i <= ol; ++i) osum += Pb[(size_t)(os_ + i) * 512 + 256 + tid];
        float x = asum / (float)(al + 1) + osum / (float)(ol + 1)
                + Wtrip[(size_t)(512 + sid[row]) * 256 + tid] + btrip[tid];
        node[(size_t)row * 256 + tid] = x;
        nodeh[(size_t)row * 256 + tid] = __float2bfloat16(x);
        float lx = x >= 0.f ? x : SLOPEC * x;
        float s1 = lx * Wattn[tid];
        float s2 = lx * Wattn[256 + tid];
        #pragma unroll
        for (int o = 32; o; o >>= 1) {
            s1 += __shfl_down(s1, o);
            s2 += __shfl_down(s2, o);
        }
        if ((tid & 63) == 0) { red[0][tid >> 6] = s1; red[1][tid >> 6] = s2; }
        __syncthreads();
        if (tid == 0) {
            atg[row] = red[0][0] + red[0][1] + red[0][2] + red[0][3];
            asr[row] = red[1][0] + red[1][1] + red[1][2] + red[1][3];
        }
    } else if (row == ROWS) {
        if (tid < Bn) bflag[tid] = 0;
        #pragma unroll
        for (int e = 0; e < 2; ++e) {
            float x = Eemb[e * 256 + tid];
            float lx = x >= 0.f ? x : SLOPEC * x;
            float s = lx * Wattn[512 + tid];
            #pragma unroll
            for (int o = 32; o; o >>= 1) s += __shfl_down(s, o);
            if ((tid & 63) == 0) red[0][tid >> 6] = s;
            __syncthreads();
            if (tid == 0) ae[e] = red[0][0] + red[0][1] + red[0][2] + red[0][3];
            __syncthreads();
        }
    } else if (row <= ROWS + 8) {
        // ve[e][n] = sum_k Eemb[e][k] * Wgat[256+k][n]; 8 blocks x 32 cols
        int j = row - (ROWS + 1);
        int n0 = j << 5;
        int nl = tid & 31, kg = tid >> 5;   // 8 k-groups
        float p0 = 0.f, p1 = 0.f;
        for (int kk = 0; kk < 32; ++kk) {
            int k = (kg << 5) + kk;
            float w = Wgat[(size_t)(256 + k) * 256 + n0 + nl];
            p0 += Eemb[k] * w;
            p1 += Eemb[256 + k] * w;
        }
        vr0[kg][nl] = p0; vr1[kg][nl] = p1;
        __syncthreads();
        if (tid < 32) {
            float s0 = 0.f, s1 = 0.f;
            #pragma unroll
            for (int g = 0; g < 8; ++g) { s0 += vr0[g][tid]; s1 += vr1[g][tid]; }
            ve[n0 + tid] = s0;
            ve[256 + n0 + tid] = s1;
        }
    } else {
        // WgT[n][k] = bf16(Wgat[k][n]) for k<256; 64 blocks x 4 k-rows
        int j = row - (ROWS + 9);
        #pragma unroll
        for (int r = 0; r < 4; ++r) {
            int k = (j << 2) + r;
            float v = Wgat[(size_t)k * 256 + tid];
            WgT[(size_t)tid * 256 + k] = __float2bfloat16(v);
        }
    }
}

// ---------------- nodeW = nodeh @ WgT^T via bf16 MFMA  (M=16384,K=256,N=256) ----------------
__global__ __launch_bounds__(256) void k_nodeW(const __hip_bfloat16* __restrict__ Ah,
        const __hip_bfloat16* __restrict__ BT, float* __restrict__ C) {
    int wave = threadIdx.x >> 6;
    int lane = threadIdx.x & 63;
    int m0 = (blockIdx.x << 6) + (wave << 4);   // wave's 16 output rows
    int n0 = blockIdx.y << 6;
    int fr = lane & 15;
    int kq = (lane >> 4) << 3;
    f32x4 acc[4] = {};
    for (int k0 = 0; k0 < 256; k0 += 32) {
        bf16x8 a = *(const bf16x8*)(Ah + (size_t)(m0 + fr) * 256 + k0 + kq);
        #pragma unroll
        for (int nf = 0; nf < 4; ++nf) {
            bf16x8 b = *(const bf16x8*)(BT + (size_t)(n0 + (nf << 4) + fr) * 256 + k0 + kq);
            acc[nf] = __builtin_amdgcn_mfma_f32_16x16x32_bf16(a, b, acc[nf], 0, 0, 0);
        }
    }
    int r0 = (lane >> 4) << 2;
    #pragma unroll
    for (int nf = 0; nf < 4; ++nf)
        #pragma unroll
        for (int r = 0; r < 4; ++r)
            C[(size_t)(m0 + r0 + r) * 256 + n0 + (nf << 4) + fr] = acc[nf][r];
}

// ---------------- sparse edges + softmax + fused GAT epilogue;
//                  each block ALSO copies 8 bulk rows (interleaved for BW/latency overlap) ----------------
__global__ __launch_bounds__(256) void k_edges(
        const float* __restrict__ node, const float* __restrict__ nodeW,
        const float* __restrict__ atg, const float* __restrict__ asr,
        const float* __restrict__ ae, const float* __restrict__ battn,
        const float* __restrict__ ve, const float* __restrict__ bgat,
        const int* __restrict__ ast, const int* __restrict__ alen,
        const int* __restrict__ ost, const int* __restrict__ olen,
        const float* __restrict__ emb, float* __restrict__ out,
        float* __restrict__ nadd, int* __restrict__ bflag) {
    int tgt = blockIdx.x;
    int b = tgt >> 9;
    int base = b << 9;
    int tid = threadIdx.x;
    int wv = tid >> 6;
    int lane = tid & 63;

    // ---- phase 0: fire-and-forget bulk copy of 8 out rows (2 float4/thread) ----
    {
        const f32x4* s4 = (const f32x4*)emb;
        f32x4* d4 = (f32x4*)out;
        #pragma unroll
        for (int i = 0; i < 2; ++i) {
            int idx = tid + (i << 8);           // 0..511
            int cr = (tgt << 3) + (idx >> 6);   // global copy row
            if (cr < CROWS) {
                int b2 = cr / (Ln - 128);
                int r2 = 128 + cr - b2 * (Ln - 128);
                size_t o4 = ((size_t)b2 * Ln + r2) * 64 + (idx & 63);
                d4[o4] = s4[o4];
            }
        }
    }

    __shared__ unsigned long long s_mask[8];
    __shared__ unsigned char s_em[512];
    __shared__ float s_s0[512], s_s1[512];
    __shared__ float s_w0[512], s_w1[512];
    __shared__ float s_fin[2];
    __shared__ int s_has;

    int at_s = ast[tgt], at_l = alen[tgt];
    int ot_s = ost[tgt], ot_l = olen[tgt];

    // phase 1: exact span-match candidates (ballot-packed)
    #pragma unroll
    for (int p = 0; p < 2; ++p) {
        int lsrc = tid + (p << 8);
        int gs = base + lsrc;
        bool self = (gs == tgt);
        bool sa = (ast[gs] == at_s) && (alen[gs] == at_l) && !self;
        bool so = (ost[gs] == ot_s) && (olen[gs] == ot_l) && !self;
        unsigned char em = (unsigned char)((sa ? 1 : 0) | ((so ? 1 : 0) << 1));
        s_em[lsrc] = em;
        unsigned long long bal = __ballot(em != 0);
        if ((tid & 63) == 0) s_mask[(p << 2) + (tid >> 6)] = bal;
    }
    __syncthreads();

    float xt = node[(size_t)tgt * 256 + tid];
    f32x4 xt4 = *(const f32x4*)(node + (size_t)tgt * 256 + (lane << 2));
    float a_t = atg[tgt];
    float ae0 = ae[0], ae1 = ae[1], b0 = battn[0];

    // phase 2: wave-parallel exact fp32 dots (candidate i -> wave i%4); no block syncs
    {
        int ci = 0;
        for (int w = 0; w < 8; ++w) {
            unsigned long long m = s_mask[w];
            while (m) {
                int bit = __builtin_ctzll(m);
                m &= m - 1;
                if ((ci++ & 3) != wv) continue;
                int lsrc = (w << 6) + bit;
                int gs = base + lsrc;
                f32x4 y = *(const f32x4*)(node + (size_t)gs * 256 + (lane << 2));
                float p = xt4.x * y.x + xt4.y * y.y + xt4.z * y.z + xt4.w * y.w;
                #pragma unroll
                for (int o = 32; o; o >>= 1) p += __shfl_xor(p, o);
                if (lane == 0) {
                    float sc0 = NEGSENT, sc1 = NEGSENT;
                    if (p > 0.f) {
                        float bs = a_t + asr[gs] + b0;
                        unsigned char em = s_em[lsrc];
                        if (em & 1) sc0 = bs + ae0;
                        if (em & 2) sc1 = bs + ae1;
                    }
                    s_s0[lsrc] = sc0; s_s1[lsrc] = sc1;
                }
            }
        }
    }
    __syncthreads();

    // phase 3: softmax over edge list (thread 0; few candidates)
    if (tid == 0) {
        float mx = NEGSENT;
        for (int w = 0; w < 8; ++w) {
            unsigned long long m = s_mask[w];
            while (m) {
                int l = (w << 6) + __builtin_ctzll(m); m &= m - 1;
                mx = fmaxf(mx, fmaxf(s_s0[l], s_s1[l]));
            }
        }
        float se0 = 0.f, se1 = 0.f;
        int has = mx > -1e29f ? 1 : 0;
        if (has) {
            float den = 0.f;
            for (int w = 0; w < 8; ++w) {
                unsigned long long m = s_mask[w];
                while (m) {
                    int l = (w << 6) + __builtin_ctzll(m); m &= m - 1;
                    den += expf(s_s0[l] - mx) + expf(s_s1[l] - mx);
                }
            }
            float rden = 1.f / den;
            for (int w = 0; w < 8; ++w) {
                unsigned long long m = s_mask[w];
                while (m) {
                    int l = (w << 6) + __builtin_ctzll(m); m &= m - 1;
                    float e0 = expf(s_s0[l] - mx) * rden;
                    float e1 = expf(s_s1[l] - mx) * rden;
                    s_w0[l] = e0; s_w1[l] = e1;
                    se0 += e0; se1 += e1;
                }
            }
            bflag[b] = 1;
        }
        s_fin[0] = se0; s_fin[1] = se1; s_has = has;
    }
    __syncthreads();

    // phase 4: aggregate nodeW + rank-2 edge term, relu, node fallback
    float res;
    if (s_has) {
        float aggW = 0.f;
        for (int w = 0; w < 8; ++w) {
            unsigned long long m = s_mask[w];
            while (m) {
                int lsrc = (w << 6) + __builtin_ctzll(m); m &= m - 1;
                float wt = s_w0[lsrc] + s_w1[lsrc];
                aggW += wt * nodeW[(size_t)(base + lsrc) * 256 + tid];
            }
        }
        float v = aggW + s_fin[0] * ve[tid] + s_fin[1] * ve[256 + tid] + bgat[tid];
        res = fmaxf(v, 0.f);
    } else {
        res = xt;
    }
    nadd[(size_t)tgt * 256 + tid] = res;
}

// ---------------- out rows<128: emb + ballot-gathered scatter-add ----------------
__global__ __launch_bounds__(256) void k_scatter(const float* __restrict__ emb,
        const float* __restrict__ nadd,
        const int* __restrict__ ast, const int* __restrict__ ost,
        const int* __restrict__ bflag, float* __restrict__ out) {
    int b = blockIdx.x >> 7;
    int r = blockIdx.x & 127;
    int tid = threadIdx.x;
    __shared__ int cen[512];
    __shared__ unsigned long long s_mask[8];
    for (int n = tid; n < 512; n += 256)
        cen[n] = (ast[(b << 9) + n] + ost[(b << 9) + n]) >> 1;
    __syncthreads();
    #pragma unroll
    for (int p = 0; p < 2; ++p) {
        int n = tid + (p << 8);
        unsigned long long bal = __ballot(cen[n] == r);
        if ((tid & 63) == 0) s_mask[(p << 2) + (tid >> 6)] = bal;
    }
    __syncthreads();
    size_t o = ((size_t)b * Ln + r) * 256 + tid;
    float acc = emb[o];
    if (bflag[b]) {
        for (int w = 0; w < 8; ++w) {
            unsigned long long m = s_mask[w];
            while (m) {
                int n = (w << 6) + __builtin_ctzll(m); m &= m - 1;
                acc += nadd[((size_t)(b << 9) + n) * 256 + tid];
            }
        }
    }
    out[o] = acc;
}

extern "C" void kernel_launch(void* const* d_in, const int* in_sizes, int n_in,
                              void* d_out, int out_size, void* d_ws, size_t ws_size,
                              hipStream_t stream) {
    const float* emb   = (const float*)d_in[0];
    const float* Wtrip = (const float*)d_in[1];
    const float* btrip = (const float*)d_in[2];
    const float* Eemb  = (const float*)d_in[3];
    const float* Wattn = (const float*)d_in[4];
    const float* battn = (const float*)d_in[5];
    const float* Wgat  = (const float*)d_in[6];
    const float* bgat  = (const float*)d_in[7];
    const int* ast  = (const int*)d_in[8];
    const int* alen = (const int*)d_in[9];
    const int* ost  = (const int*)d_in[10];
    const int* olen = (const int*)d_in[11];
    const int* sid  = (const int*)d_in[12];
    float* out = (float*)d_out;

    float* ws    = (float*)d_ws;
    float* PQ    = ws;                                    // [Bn*LR*512]  8.9 MB
    float* node  = PQ + (size_t)Bn * LR * 512;            // [ROWS*256] fp32
    float* nodeW = node + (size_t)ROWS * 256;             // [ROWS*256] fp32
    float* nadd  = nodeW + (size_t)ROWS * 256;            // [ROWS*256] fp32
    float* atg   = nadd + (size_t)ROWS * 256;             // [ROWS]
    float* asr   = atg + ROWS;                            // [ROWS]
    float* ae    = asr + ROWS;                            // [2]
    float* ve    = ae + 2;                                // [512]
    int* bflag   = (int*)(ve + 512);                      // [Bn]
    __hip_bfloat16* nodeh = (__hip_bfloat16*)(bflag + Bn + 32);   // [ROWS*256] bf16
    __hip_bfloat16* WgT   = nodeh + (size_t)ROWS * 256;           // [256*256] bf16

    k_pq<<<dim3(Bn * LR / 64, 8), 256, 0, stream>>>(emb, Wtrip, PQ);
    k_combine<<<ROWS + 73, 256, 0, stream>>>(PQ, Wtrip, btrip, sid, ast, alen, ost, olen,
                                             Wattn, Eemb, Wgat, node, nodeh, WgT,
                                             atg, asr, ae, ve, bflag);
    k_nodeW<<<dim3(ROWS / 64, 4), 256, 0, stream>>>(nodeh, WgT, nodeW);
    k_edges<<<ROWS, 256, 0, stream>>>(node, nodeW, atg, asr, ae, battn, ve, bgat,
                                      ast, alen, ost, olen, emb, out, nadd, bflag);
    k_scatter<<<Bn * 128, 256, 0, stream>>>(emb, nadd, ast, ost, bflag, out);
}

// Round 7
// 160.246 us; speedup vs baseline: 2.1159x; 1.0940x over previous
//
#include <hip/hip_runtime.h>
#include <hip/hip_bf16.h>
#include <math.h>

#define Bn 32
#define Ln 4096
#define Hn 256
#define Nn 512
#define ROWS (Bn*Nn)   // 16384
#define LR 136         // emb rows used per batch (st<128, len<8 -> ed<=134)
#define SLOPEC 0.2f
#define NEGSENT -1e30f
#define CROWS (Bn*(Ln-128))   // 126976 rows to bulk-copy (rows 128..4095)
// copy partition (in rows): k_pq [0,16384), k_nodeW [16384,28672), k_edges [28672,126976)

typedef __attribute__((ext_vector_type(8))) short bf16x8;
typedef __attribute__((ext_vector_type(4))) float f32x4;

__device__ __forceinline__ void copy_slot(const f32x4* __restrict__ s4,
                                          f32x4* __restrict__ d4, long slot) {
    int cr = (int)(slot >> 6);
    int b2 = cr / (Ln - 128);
    int r2 = 128 + cr - b2 * (Ln - 128);
    size_t o4 = ((size_t)b2 * Ln + r2) * 64 + (slot & 63);
    d4[o4] = s4[o4];
}

// ---------------- PQ = emb[:, :136] @ [Wtrip_top | Wtrip_bot]  (M=4352,K=256,N=512)
//                  + interleaved copy of 16384 out rows ----------------
__global__ __launch_bounds__(256) void k_pq(const float* __restrict__ emb,
        const float* __restrict__ Wtrip, float* __restrict__ PQ,
        float* __restrict__ out) {
    __shared__ float Als[32][68];
    __shared__ float Bls[32][64];
    int tid = threadIdx.x;
    {   // fire-and-forget copy share: 2048 slots/block, guard at 16384*64
        int bid = blockIdx.y * 68 + blockIdx.x;
        const f32x4* s4 = (const f32x4*)emb;
        f32x4* d4 = (f32x4*)out;
        #pragma unroll
        for (int i = 0; i < 8; ++i) {
            long slot = (long)bid * 2048 + i * 256 + tid;
            if (slot < 1048576L) copy_slot(s4, d4, slot);
        }
    }
    int m0 = blockIdx.x << 6;
    int n0 = blockIdx.y << 6;
    int r0 = (tid & 15) << 2;
    int c0 = (tid >> 4) << 2;
    const float* Bbase = Wtrip + ((n0 >= 256) ? 256 * 256 : 0) + (n0 & 255);
    float acc[4][4] = {};
    for (int kk = 0; kk < 256; kk += 32) {
        __syncthreads();
        #pragma unroll
        for (int p = 0; p < 2; ++p) {   // A: 64 rows x 32 k (k-major LDS)
            int idx = tid + (p << 8);
            int row = idx >> 3;
            int kq = (idx & 7) << 2;
            int m = m0 + row;
            int b = m / LR;
            int l = m - b * LR;
            const float4 v = *(const float4*)(emb + (size_t)(b * Ln + l) * 256 + kk + kq);
            Als[kq + 0][row] = v.x; Als[kq + 1][row] = v.y;
            Als[kq + 2][row] = v.z; Als[kq + 3][row] = v.w;
        }
        #pragma unroll
        for (int p = 0; p < 2; ++p) {   // B: 32 k x 64 cols
            int idx = tid + (p << 8);
            int k = idx >> 4;
            int hq = (idx & 15) << 2;
            *(float4*)(&Bls[k][hq]) = *(const float4*)(Bbase + (size_t)(kk + k) * 256 + hq);
        }
        __syncthreads();
        #pragma unroll
        for (int k = 0; k < 32; ++k) {
            float4 a  = *(const float4*)(&Als[k][r0]);
            float4 bv = *(const float4*)(&Bls[k][c0]);
            acc[0][0] += a.x*bv.x; acc[0][1] += a.x*bv.y; acc[0][2] += a.x*bv.z; acc[0][3] += a.x*bv.w;
            acc[1][0] += a.y*bv.x; acc[1][1] += a.y*bv.y; acc[1][2] += a.y*bv.z; acc[1][3] += a.y*bv.w;
            acc[2][0] += a.z*bv.x; acc[2][1] += a.z*bv.y; acc[2][2] += a.z*bv.z; acc[2][3] += a.z*bv.w;
            acc[3][0] += a.w*bv.x; acc[3][1] += a.w*bv.y; acc[3][2] += a.w*bv.z; acc[3][3] += a.w*bv.w;
        }
    }
    #pragma unroll
    for (int i = 0; i < 4; ++i)
        #pragma unroll
        for (int j = 0; j < 4; ++j)
            PQ[(size_t)(m0 + r0 + i) * 512 + n0 + c0 + j] = acc[i][j];
}

// ---------------- span combine -> node (fp32) + nodeh (bf16), fused stats;
//                  extra blocks: ae+bflag / ve (8 blocks) / WgT transpose (64 blocks) ----------------
__global__ __launch_bounds__(256) void k_combine(const float* __restrict__ PQ,
        const float* __restrict__ Wtrip, const float* __restrict__ btrip,
        const int* __restrict__ sid,
        const int* __restrict__ ast, const int* __restrict__ alen,
        const int* __restrict__ ost, const int* __restrict__ olen,
        const float* __restrict__ Wattn, const float* __restrict__ Eemb,
        const float* __restrict__ Wgat,
        float* __restrict__ node, __hip_bfloat16* __restrict__ nodeh,
        __hip_bfloat16* __restrict__ WgT,
        float* __restrict__ atg, float* __restrict__ asr,
        float* __restrict__ ae, float* __restrict__ ve, int* __restrict__ bflag) {
    int row = blockIdx.x;
    int tid = threadIdx.x;
    __shared__ float red[2][4];
    __shared__ float vr0[8][32], vr1[8][32];
    if (row < ROWS) {
        int b = row >> 9;
        int as_ = ast[row], al = alen[row];
        int os_ = ost[row], ol = olen[row];
        const float* Pb = PQ + (size_t)b * LR * 512;
        float asum = 0.f;
        for (int i = 0; i <= al; ++i) asum += Pb[(size_t)(as_ + i) * 512 + tid];
        float osum = 0.f;
        for (int i = 0; i <= ol; ++i) osum += Pb[(size_t)(os_ + i) * 512 + 256 + tid];
        float x = asum / (float)(al + 1) + osum / (float)(ol + 1)
                + Wtrip[(size_t)(512 + sid[row]) * 256 + tid] + btrip[tid];
        node[(size_t)row * 256 + tid] = x;
        nodeh[(size_t)row * 256 + tid] = __float2bfloat16(x);
        float lx = x >= 0.f ? x : SLOPEC * x;
        float s1 = lx * Wattn[tid];
        float s2 = lx * Wattn[256 + tid];
        #pragma unroll
        for (int o = 32; o; o >>= 1) {
            s1 += __shfl_down(s1, o);
            s2 += __shfl_down(s2, o);
        }
        if ((tid & 63) == 0) { red[0][tid >> 6] = s1; red[1][tid >> 6] = s2; }
        __syncthreads();
        if (tid == 0) {
            atg[row] = red[0][0] + red[0][1] + red[0][2] + red[0][3];
            asr[row] = red[1][0] + red[1][1] + red[1][2] + red[1][3];
        }
    } else if (row == ROWS) {
        if (tid < Bn) bflag[tid] = 0;
        #pragma unroll
        for (int e = 0; e < 2; ++e) {
            float x = Eemb[e * 256 + tid];
            float lx = x >= 0.f ? x : SLOPEC * x;
            float s = lx * Wattn[512 + tid];
            #pragma unroll
            for (int o = 32; o; o >>= 1) s += __shfl_down(s, o);
            if ((tid & 63) == 0) red[0][tid >> 6] = s;
            __syncthreads();
            if (tid == 0) ae[e] = red[0][0] + red[0][1] + red[0][2] + red[0][3];
            __syncthreads();
        }
    } else if (row <= ROWS + 8) {
        // ve[e][n] = sum_k Eemb[e][k] * Wgat[256+k][n]; 8 blocks x 32 cols
        int j = row - (ROWS + 1);
        int n0 = j << 5;
        int nl = tid & 31, kg = tid >> 5;   // 8 k-groups
        float p0 = 0.f, p1 = 0.f;
        for (int kk = 0; kk < 32; ++kk) {
            int k = (kg << 5) + kk;
            float w = Wgat[(size_t)(256 + k) * 256 + n0 + nl];
            p0 += Eemb[k] * w;
            p1 += Eemb[256 + k] * w;
        }
        vr0[kg][nl] = p0; vr1[kg][nl] = p1;
        __syncthreads();
        if (tid < 32) {
            float s0 = 0.f, s1 = 0.f;
            #pragma unroll
            for (int g = 0; g < 8; ++g) { s0 += vr0[g][tid]; s1 += vr1[g][tid]; }
            ve[n0 + tid] = s0;
            ve[256 + n0 + tid] = s1;
        }
    } else {
        // WgT[n][k] = bf16(Wgat[k][n]) for k<256; 64 blocks x 4 k-rows
        int j = row - (ROWS + 9);
        #pragma unroll
        for (int r = 0; r < 4; ++r) {
            int k = (j << 2) + r;
            float v = Wgat[(size_t)k * 256 + tid];
            WgT[(size_t)tid * 256 + k] = __float2bfloat16(v);
        }
    }
}

// ---------------- nodeW = nodeh @ WgT^T via bf16 MFMA  (M=16384,K=256,N=256)
//                  + interleaved copy of 12288 out rows ----------------
__global__ __launch_bounds__(256) void k_nodeW(const __hip_bfloat16* __restrict__ Ah,
        const __hip_bfloat16* __restrict__ BT, float* __restrict__ C,
        const float* __restrict__ emb, float* __restrict__ out) {
    {   // copy share: 768 slots/block exact (1024 blocks)
        int bid = blockIdx.y * 256 + blockIdx.x;
        const f32x4* s4 = (const f32x4*)emb;
        f32x4* d4 = (f32x4*)out;
        #pragma unroll
        for (int i = 0; i < 3; ++i)
            copy_slot(s4, d4, 1048576L + (long)bid * 768 + i * 256 + threadIdx.x);
    }
    int wave = threadIdx.x >> 6;
    int lane = threadIdx.x & 63;
    int m0 = (blockIdx.x << 6) + (wave << 4);   // wave's 16 output rows
    int n0 = blockIdx.y << 6;
    int fr = lane & 15;
    int kq = (lane >> 4) << 3;
    f32x4 acc[4] = {};
    for (int k0 = 0; k0 < 256; k0 += 32) {
        bf16x8 a = *(const bf16x8*)(Ah + (size_t)(m0 + fr) * 256 + k0 + kq);
        #pragma unroll
        for (int nf = 0; nf < 4; ++nf) {
            bf16x8 b = *(const bf16x8*)(BT + (size_t)(n0 + (nf << 4) + fr) * 256 + k0 + kq);
            acc[nf] = __builtin_amdgcn_mfma_f32_16x16x32_bf16(a, b, acc[nf], 0, 0, 0);
        }
    }
    int r0 = (lane >> 4) << 2;
    #pragma unroll
    for (int nf = 0; nf < 4; ++nf)
        #pragma unroll
        for (int r = 0; r < 4; ++r)
            C[(size_t)(m0 + r0 + r) * 256 + n0 + (nf << 4) + fr] = acc[nf][r];
}

// ---------------- sparse edges: wave-per-target, zero barriers, all-register;
//                  + interleaved copy of 98304 out rows (24/block) ----------------
__global__ __launch_bounds__(256) void k_edges(
        const float* __restrict__ node, const float* __restrict__ nodeW,
        const float* __restrict__ atg, const float* __restrict__ asr,
        const float* __restrict__ ae, const float* __restrict__ battn,
        const float* __restrict__ ve, const float* __restrict__ bgat,
        const int* __restrict__ ast, const int* __restrict__ alen,
        const int* __restrict__ ost, const int* __restrict__ olen,
        const float* __restrict__ emb, float* __restrict__ out,
        float* __restrict__ nadd, int* __restrict__ bflag) {
    int bid = blockIdx.x;
    int tid = threadIdx.x;
    int wv = tid >> 6, lane = tid & 63;

    {   // copy share: 1536 slots/block exact (4096 blocks)
        const f32x4* s4 = (const f32x4*)emb;
        f32x4* d4 = (f32x4*)out;
        #pragma unroll
        for (int i = 0; i < 6; ++i)
            copy_slot(s4, d4, 1835008L + (long)bid * 1536 + i * 256 + tid);
    }

    int tgt = (bid << 2) + wv;
    int b = tgt >> 9, base = b << 9, lt = tgt & 511;

    int at_s = ast[tgt], at_l = alen[tgt];
    int ot_s = ost[tgt], ot_l = olen[tgt];

    // phase 1: span-match ballots, wave-private
    unsigned long long mA[8], mO[8];
    #pragma unroll
    for (int j = 0; j < 8; ++j) {
        int ls = (j << 6) + lane;
        int gs = base + ls;
        bool self = (ls == lt);
        bool sa = (ast[gs] == at_s) && (alen[gs] == at_l) && !self;
        bool so = (ost[gs] == ot_s) && (olen[gs] == ot_l) && !self;
        mA[j] = __ballot(sa);
        mO[j] = __ballot(so);
    }

    f32x4 xt4 = *(const f32x4*)(node + (size_t)tgt * 256 + (lane << 2));
    float a_t = atg[tgt];
    float ae0 = ae[0], ae1 = ae[1], b0 = battn[0];

    // phase 2: exact fp32 dot per candidate; scores held by owner lane (slot = word j)
    float s0a[8], s1a[8];
    unsigned long long mK[8];
    #pragma unroll
    for (int j = 0; j < 8; ++j) {
        s0a[j] = NEGSENT; s1a[j] = NEGSENT;
        unsigned long long m = mA[j] | mO[j];
        while (m) {
            int bit = __builtin_ctzll(m); m &= m - 1;
            int gs = base + (j << 6) + bit;
            f32x4 y = *(const f32x4*)(node + (size_t)gs * 256 + (lane << 2));
            float p = xt4.x * y.x + xt4.y * y.y + xt4.z * y.z + xt4.w * y.w;
            #pragma unroll
            for (int o = 32; o; o >>= 1) p += __shfl_xor(p, o);
            if (p > 0.f && lane == bit) {
                float bs = a_t + asr[gs] + b0;
                if ((mA[j] >> bit) & 1) s0a[j] = bs + ae0;
                if ((mO[j] >> bit) & 1) s1a[j] = bs + ae1;
            }
        }
        mK[j] = __ballot(s0a[j] > -1e29f || s1a[j] > -1e29f);
    }

    // phase 3: wave-parallel softmax stats
    float mx = NEGSENT;
    #pragma unroll
    for (int j = 0; j < 8; ++j) mx = fmaxf(mx, fmaxf(s0a[j], s1a[j]));
    #pragma unroll
    for (int o = 32; o; o >>= 1) mx = fmaxf(mx, __shfl_xor(mx, o));
    bool has = mx > -1e29f;

    float se0 = 0.f, se1 = 0.f;
    #pragma unroll
    for (int j = 0; j < 8; ++j) {
        se0 += expf(s0a[j] - mx);   // expf(-1e30 - mx) == 0 for absent slots
        se1 += expf(s1a[j] - mx);
    }
    #pragma unroll
    for (int o = 32; o; o >>= 1) { se0 += __shfl_xor(se0, o); se1 += __shfl_xor(se1, o); }
    float rden = 1.f / (se0 + se1);

    // phase 4: aggregate nodeW + rank-2 edge term, relu, node fallback
    f32x4 res;
    if (has) {
        f32x4 agg4 = {0.f, 0.f, 0.f, 0.f};
        #pragma unroll
        for (int j = 0; j < 8; ++j) {
            unsigned long long m = mK[j];
            while (m) {
                int bit = __builtin_ctzll(m); m &= m - 1;
                int gs = base + (j << 6) + bit;
                float w0 = __shfl(s0a[j], bit);
                float w1 = __shfl(s1a[j], bit);
                float wt = (expf(w0 - mx) + expf(w1 - mx)) * rden;
                const f32x4 nw = *(const f32x4*)(nodeW + (size_t)gs * 256 + (lane << 2));
                agg4.x += wt * nw.x; agg4.y += wt * nw.y;
                agg4.z += wt * nw.z; agg4.w += wt * nw.w;
            }
        }
        f32x4 v1 = *(const f32x4*)(ve + (lane << 2));
        f32x4 v2 = *(const f32x4*)(ve + 256 + (lane << 2));
        f32x4 bg = *(const f32x4*)(bgat + (lane << 2));
        float c0 = se0 * rden, c1 = se1 * rden;
        res.x = fmaxf(agg4.x + c0 * v1.x + c1 * v2.x + bg.x, 0.f);
        res.y = fmaxf(agg4.y + c0 * v1.y + c1 * v2.y + bg.y, 0.f);
        res.z = fmaxf(agg4.z + c0 * v1.z + c1 * v2.z + bg.z, 0.f);
        res.w = fmaxf(agg4.w + c0 * v1.w + c1 * v2.w + bg.w, 0.f);
        if (lane == 0) bflag[b] = 1;
    } else {
        res = xt4;
    }
    *(f32x4*)(nadd + (size_t)tgt * 256 + (lane << 2)) = res;
}

// ---------------- out rows<128: emb + ballot-gathered scatter-add ----------------
__global__ __launch_bounds__(256) void k_scatter(const float* __restrict__ emb,
        const float* __restrict__ nadd,
        const int* __restrict__ ast, const int* __restrict__ ost,
        const int* __restrict__ bflag, float* __restrict__ out) {
    int b = blockIdx.x >> 7;
    int r = blockIdx.x & 127;
    int tid = threadIdx.x;
    __shared__ int cen[512];
    __shared__ unsigned long long s_mask[8];
    for (int n = tid; n < 512; n += 256)
        cen[n] = (ast[(b << 9) + n] + ost[(b << 9) + n]) >> 1;
    __syncthreads();
    #pragma unroll
    for (int p = 0; p < 2; ++p) {
        int n = tid + (p << 8);
        unsigned long long bal = __ballot(cen[n] == r);
        if ((tid & 63) == 0) s_mask[(p << 2) + (tid >> 6)] = bal;
    }
    __syncthreads();
    size_t o = ((size_t)b * Ln + r) * 256 + tid;
    float acc = emb[o];
    if (bflag[b]) {
        for (int w = 0; w < 8; ++w) {
            unsigned long long m = s_mask[w];
            while (m) {
                int n = (w << 6) + __builtin_ctzll(m); m &= m - 1;
                acc += nadd[((size_t)(b << 9) + n) * 256 + tid];
            }
        }
    }
    out[o] = acc;
}

extern "C" void kernel_launch(void* const* d_in, const int* in_sizes, int n_in,
                              void* d_out, int out_size, void* d_ws, size_t ws_size,
                              hipStream_t stream) {
    const float* emb   = (const float*)d_in[0];
    const float* Wtrip = (const float*)d_in[1];
    const float* btrip = (const float*)d_in[2];
    const float* Eemb  = (const float*)d_in[3];
    const float* Wattn = (const float*)d_in[4];
    const float* battn = (const float*)d_in[5];
    const float* Wgat  = (const float*)d_in[6];
    const float* bgat  = (const float*)d_in[7];
    const int* ast  = (const int*)d_in[8];
    const int* alen = (const int*)d_in[9];
    const int* ost  = (const int*)d_in[10];
    const int* olen = (const int*)d_in[11];
    const int* sid  = (const int*)d_in[12];
    float* out = (float*)d_out;

    float* ws    = (float*)d_ws;
    float* PQ    = ws;                                    // [Bn*LR*512]  8.9 MB
    float* node  = PQ + (size_t)Bn * LR * 512;            // [ROWS*256] fp32
    float* nodeW = node + (size_t)ROWS * 256;             // [ROWS*256] fp32
    float* nadd  = nodeW + (size_t)ROWS * 256;            // [ROWS*256] fp32
    float* atg   = nadd + (size_t)ROWS * 256;             // [ROWS]
    float* asr   = atg + ROWS;                            // [ROWS]
    float* ae    = asr + ROWS;                            // [2]
    float* ve    = ae + 2;                                // [512]
    int* bflag   = (int*)(ve + 512);                      // [Bn]
    __hip_bfloat16* nodeh = (__hip_bfloat16*)(bflag + Bn + 32);   // [ROWS*256] bf16
    __hip_bfloat16* WgT   = nodeh + (size_t)ROWS * 256;           // [256*256] bf16

    k_pq<<<dim3(Bn * LR / 64, 8), 256, 0, stream>>>(emb, Wtrip, PQ, out);
    k_combine<<<ROWS + 73, 256, 0, stream>>>(PQ, Wtrip, btrip, sid, ast, alen, ost, olen,
                                             Wattn, Eemb, Wgat, node, nodeh, WgT,
                                             atg, asr, ae, ve, bflag);
    k_nodeW<<<dim3(ROWS / 64, 4), 256, 0, stream>>>(nodeh, WgT, nodeW, emb, out);
    k_edges<<<ROWS / 4, 256, 0, stream>>>(node, nodeW, atg, asr, ae, battn, ve, bgat,
                                          ast, alen, ost, olen, emb, out, nadd, bflag);
    k_scatter<<<Bn * 128, 256, 0, stream>>>(emb, nadd, ast, ost, bflag, out);
}